// Round 12
// baseline (869.825 us; speedup 1.0000x reference)
//
#include <hip/hip_runtime.h>
#include <hip/hip_bf16.h>
#include <math.h>

// ---------------- problem dims (fixed by setup_inputs) ----------------
#define BTOT 1536            // B*T = 32*48
// linguistic
#define EL 300
#define ELP 320              // padded CIN (10 c-chunks of 32)
#define WL_ 33
#define CL 128
#define LOUTL 29
#define KPL 1600
// acoustic
#define EA 988
#define EAP 992              // 31 c-chunks
#define WA_ 50
#define CA 256
#define LOUTA 41
#define KPA 9920
// emotient
#define EE 20
#define WE_ 30
#define HH 128
#define CE 64
#define LOUTE 28
#define KPE 384
// fallback K dims
#define KDIML 1500
#define KDIMA 9880
#define KDIME 384

typedef __attribute__((ext_vector_type(4))) float f32x4;
typedef __attribute__((ext_vector_type(8))) short short8;

// RNE float->bf16 (inputs finite)
__device__ __forceinline__ unsigned short f2bf(float f) {
    unsigned int x = __float_as_uint(f);
    unsigned int r = (x + 0x7fffu + ((x >> 16) & 1u)) >> 16;
    return (unsigned short)r;
}

__device__ __forceinline__ float sigmf(float x) {
    return __builtin_amdgcn_rcpf(1.f + __expf(-x));
}
__device__ __forceinline__ float tanh_fast(float x) {
    return 1.f - 2.f * __builtin_amdgcn_rcpf(1.f + __expf(2.f * x));
}

#define GLD16(gp, lp) __builtin_amdgcn_global_load_lds( \
    (const __attribute__((address_space(1))) void*)(gp), \
    (__attribute__((address_space(3))) void*)(lp), 16, 0, 0)

template<int N> __device__ __forceinline__ void vmwait() {
    if constexpr (N == 0) asm volatile("s_waitcnt vmcnt(0)" ::: "memory");
    else if constexpr (N == 1) asm volatile("s_waitcnt vmcnt(1)" ::: "memory");
    else if constexpr (N == 2) asm volatile("s_waitcnt vmcnt(2)" ::: "memory");
    else if constexpr (N == 3) asm volatile("s_waitcnt vmcnt(3)" ::: "memory");
    else if constexpr (N == 4) asm volatile("s_waitcnt vmcnt(4)" ::: "memory");
    else if constexpr (N == 5) asm volatile("s_waitcnt vmcnt(5)" ::: "memory");
    else if constexpr (N == 6) asm volatile("s_waitcnt vmcnt(6)" ::: "memory");
    else if constexpr (N == 8) asm volatile("s_waitcnt vmcnt(8)" ::: "memory");
    else static_assert(N == 0, "add case");
}

// ================= fused prep kernel (everything small + all conv weights) =================
__device__ __forceinline__ void tr_one(const float* a, float* at, int R, int C, int idx) {
    int r = idx / C, c = idx - r * C;
    at[c * R + r] = a[idx];
}
template<int CIN, int CINP, int KW, int COUT, int KPAD>
__device__ __forceinline__ void wt_one(const float* w, unsigned short* wt, int idx) {
    int co = idx / KPAD;
    int p  = idx - co * KPAD;
    int k  = p / CINP;
    int c  = p - k * CINP;
    float v = 0.f;
    if (k < KW && c < CIN) v = w[(co * CIN + c) * KW + k];
    wt[idx] = f2bf(v);
}
template<bool BIG>
__global__ void prep_all(const float* hwL_Wp, float* WpTL, const float* hwL_Wg, float* WgTL,
                         const float* hwA_Wp, float* WpTA, const float* hwA_Wg, float* WgTA,
                         const float* hwE_Wp, float* WpTE, const float* hwE_Wg, float* WgTE,
                         const float* lstm_Wih, float* WihT, const float* lstm_Whh, float* WhhT,
                         const float* convL_w, unsigned short* wtL,
                         const float* convE_w, unsigned short* wtE,
                         const float* convA_w, unsigned short* wtA,
                         unsigned short* whh_bf, unsigned short* wihp_bf) {
    constexpr int S1 = 16384, S2 = 16384, S3 = 65536, S4 = 65536, S5 = 4096, S6 = 4096;
    constexpr int S7 = 512 * 20, S8 = 512 * 128;
    constexpr int S9 = 128 * KPL, S10 = 64 * KPE, S11 = 512 * 128, S12 = 512 * 32;
    constexpr int S13 = CA * KPA;
    constexpr int SMALL = S1 + S2 + S3 + S4 + S5 + S6 + S7 + S8;
    constexpr int TOTAL = BIG ? (SMALL + S9 + S10 + S11 + S12 + S13) : SMALL;
    int stride = gridDim.x * blockDim.x;
    for (int i = blockIdx.x * blockDim.x + threadIdx.x; i < TOTAL; i += stride) {
        int idx = i;
        if (idx < S1) { tr_one(hwL_Wp, WpTL, 128, 128, idx); continue; } idx -= S1;
        if (idx < S2) { tr_one(hwL_Wg, WgTL, 128, 128, idx); continue; } idx -= S2;
        if (idx < S3) { tr_one(hwA_Wp, WpTA, 256, 256, idx); continue; } idx -= S3;
        if (idx < S4) { tr_one(hwA_Wg, WgTA, 256, 256, idx); continue; } idx -= S4;
        if (idx < S5) { tr_one(hwE_Wp, WpTE, 64, 64, idx); continue; } idx -= S5;
        if (idx < S6) { tr_one(hwE_Wg, WgTE, 64, 64, idx); continue; } idx -= S6;
        if (idx < S7) { tr_one(lstm_Wih, WihT, 512, 20, idx); continue; } idx -= S7;
        if (idx < S8) { tr_one(lstm_Whh, WhhT, 512, 128, idx); continue; } idx -= S8;
        if constexpr (BIG) {
            if (idx < S9) { wt_one<EL, ELP, 5, CL, KPL>(convL_w, wtL, idx); continue; } idx -= S9;
            if (idx < S10) { wt_one<HH, HH, 3, CE, KPE>(convE_w, wtE, idx); continue; } idx -= S10;
            if (idx < S11) { whh_bf[idx] = f2bf(lstm_Whh[idx]); continue; } idx -= S11;
            if (idx < S12) { int col = idx >> 5, e = idx & 31;
                             wihp_bf[idx] = (e < 20) ? f2bf(lstm_Wih[col * 20 + e]) : (unsigned short)0;
                             continue; } idx -= S12;
            wt_one<EA, EAP, 10, CA, KPA>(convA_w, wtA, idx);
        }
    }
}

// ---------------- fp32->bf16 pad convert chunk helper ----------------
template<int CIN, int CINP>
__device__ __forceinline__ void cvt_chunk(const float* in, unsigned short* out, int idx) {
    constexpr int CH = CINP / 8;
    int row = idx / CH, c0 = (idx - row * CH) * 8;
    const float* src = in + (size_t)row * CIN + c0;
    union { short8 s; unsigned short u[8]; } o;
    if (c0 + 8 <= CIN) {
        float4 v0 = *(const float4*)src;
        float4 v1 = *(const float4*)(src + 4);
        o.u[0]=f2bf(v0.x); o.u[1]=f2bf(v0.y); o.u[2]=f2bf(v0.z); o.u[3]=f2bf(v0.w);
        o.u[4]=f2bf(v1.x); o.u[5]=f2bf(v1.y); o.u[6]=f2bf(v1.z); o.u[7]=f2bf(v1.w);
    } else {
        #pragma unroll
        for (int j = 0; j < 8; ++j) o.u[j] = (c0 + j < CIN) ? f2bf(src[j]) : (unsigned short)0;
    }
    *(short8*)(out + (size_t)row * CINP + c0) = o.s;
}

// ================= fused LSTM (blocks 0..95) + both fp32->bf16 converts (blocks 96+) =================
#define LSTM_BLOCKS 96
#define CVT_BLOCKS 1952

__global__ __launch_bounds__(512, 1)
void lstm_cvt(const float* __restrict__ x_emo,
              const unsigned short* __restrict__ wihp_bf, const unsigned short* __restrict__ whh_bf,
              const float* __restrict__ bih, const float* __restrict__ bhh,
              const int* __restrict__ lens, unsigned short* __restrict__ hbuf,
              const float* __restrict__ xa, const float* __restrict__ xl,
              unsigned short* __restrict__ outa, unsigned short* __restrict__ outl)
{
    __shared__ __align__(16) unsigned short xq[WE_ * 16 * 32];  // 30 KB
    __shared__ __align__(16) char h_s[2 * 16 * HH * 2];         // 8 KB dbuf, swizzled

    if (blockIdx.x >= LSTM_BLOCKS) {
        constexpr int NAC = (BTOT * WA_) * (EAP / 8);
        constexpr int NLC = (BTOT * WL_) * (ELP / 8);
        int stride = CVT_BLOCKS * 512;
        for (int i = (blockIdx.x - LSTM_BLOCKS) * 512 + threadIdx.x; i < NAC + NLC; i += stride) {
            if (i < NAC) cvt_chunk<EA, EAP>(xa, outa, i);
            else         cvt_chunk<EL, ELP>(xl, outl, i - NAC);
        }
        return;
    }

    // ---- LSTM path: 16 samples/block ----
    const int tid  = threadIdx.x;
    const int w    = tid >> 6;
    const int lane = tid & 63;
    const int lr   = lane & 15;
    const int lq   = lane >> 4;
    const int s0   = blockIdx.x * 16;
    const int c    = w * 16 + lr;     // gate-col within 128

    short8 bfr[4][4];
    short8 bw[4];
    float bj[4];
    #pragma unroll
    for (int g = 0; g < 4; ++g) {
        int col = g * 128 + c;
        #pragma unroll
        for (int kt = 0; kt < 4; ++kt)
            bfr[g][kt] = *(const short8*)(whh_bf + (size_t)col * 128 + kt * 32 + lq * 8);
        bw[g] = *(const short8*)(wihp_bf + (size_t)col * 32 + lq * 8);
        bj[g] = bih[col] + bhh[col];
    }
    int len4[4];
    #pragma unroll
    for (int j = 0; j < 4; ++j) len4[j] = lens[s0 + lq * 4 + j];

    for (int i = tid; i < WE_ * 16 * 32; i += 512) {
        int t = i >> 9, r = (i >> 5) & 15, e = i & 31;
        xq[i] = (e < 20) ? f2bf(x_emo[(((size_t)(s0 + r) * WE_) + t) * 20 + e]) : (unsigned short)0;
    }
    for (int i = tid; i < 2048; i += 512) ((unsigned int*)h_s)[i] = 0u;

    float c_prev[4] = {0.f, 0.f, 0.f, 0.f};
    unsigned short hb_prev[4] = {0, 0, 0, 0};
    __syncthreads();

    for (int t = 0; t < WE_; ++t) {
        const char* hsr = h_s + (t & 1) * 4096;
        char* hsw = h_s + ((t & 1) ^ 1) * 4096;
        short8 ax = *(const short8*)((const char*)xq + (size_t)(t * 16 + lr) * 64 + lq * 16);
        short8 af[4];
        #pragma unroll
        for (int kt = 0; kt < 4; ++kt)
            af[kt] = *(const short8*)(hsr + ((lr * 256 + kt * 64 + lq * 16) ^ ((lr & 7) << 4)));
        f32x4 acc[4];
        #pragma unroll
        for (int g = 0; g < 4; ++g)
            acc[g] = __builtin_amdgcn_mfma_f32_16x16x32_bf16(ax, bw[g], (f32x4){0.f,0.f,0.f,0.f}, 0, 0, 0);
        #pragma unroll
        for (int kt = 0; kt < 4; ++kt)
            #pragma unroll
            for (int g = 0; g < 4; ++g)
                acc[g] = __builtin_amdgcn_mfma_f32_16x16x32_bf16(af[kt], bfr[g][kt], acc[g], 0, 0, 0);
        #pragma unroll
        for (int j = 0; j < 4; ++j) {
            int s = lq * 4 + j;
            float zi = acc[0][j] + bj[0];
            float zf = acc[1][j] + bj[1];
            float zg = acc[2][j] + bj[2];
            float zo = acc[3][j] + bj[3];
            float si = sigmf(zi), sf = sigmf(zf), so = sigmf(zo);
            float tg = tanh_fast(zg);
            float c2 = sf * c_prev[j] + si * tg;
            float h2 = so * tanh_fast(c2);
            bool valid = (t < len4[j]);
            c_prev[j] = valid ? c2 : c_prev[j];
            unsigned short h2b = f2bf(h2);
            unsigned short hn = valid ? h2b : hb_prev[j];
            hb_prev[j] = hn;
            *(unsigned short*)(hsw + (((s * HH + c) * 2) ^ ((s & 7) << 4))) = hn;
            hbuf[(((size_t)(s0 + s) * WE_) + t) * HH + c] = valid ? h2b : (unsigned short)0;
        }
        __syncthreads();
    }
}

// ================= conv_a12: acoustic conv, 12 waves = 12 samples, grid 256 = 1 block/CU =================
// 3 waves/SIMD for LDS-read/MFMA duty-cycle overlap. A: 12 samples x 64 raw rows, double-buffered
// per c-chunk (staged 1 chunk-col per step at k0..k3, all threads). B: [128 cols][64B], 4-slot ring
// staged 3 ahead by waves 0..7 (512 thr, 1 load each). Per-step barrier; per-ROLE counted vmcnt
// (v8 rule: cap = issues(st)+issues(st-1) per role).
#define CONVA12_BLOCKS 256
__global__ __launch_bounds__(768, 3)
void conv_a12(const unsigned short* __restrict__ xb, const unsigned short* __restrict__ wt,
              const float* __restrict__ bias, float* __restrict__ pooled)
{
    constexpr int CINP = EAP, BN = 128, COUT = CA, KW = 10, LOUT = LOUTA, WIN = WA_;
    constexpr int CCH  = CINP / 32;       // 31
    constexpr int KB   = CINP * 2;        // 1984
    constexpr int KTOTB = CINP * KW * 2;
    constexpr int ABUF = 12 * 4096;       // 48 KB per parity
    constexpr int BBUF = BN * 64;         // 8 KB

    __shared__ __align__(16) char smem[2 * ABUF + 4 * BBUF];   // 131072 B

    const int tid  = threadIdx.x;
    const int lane = tid & 63;
    const int wid  = tid >> 6;            // 0..11, wave = sample
    const int lr   = lane & 15;
    const int lq   = lane >> 4;
    const int lq16 = lq * 16;
    const bool bstager = (wid < 8);

    int xcd = blockIdx.x & 7;
    int n = xcd & 1;
    int m = (xcd >> 1) * 32 + (blockIdx.x >> 3);   // 0..127

    f32x4 acc[3][8];
    #pragma unroll
    for (int i = 0; i < 3; ++i)
        #pragma unroll
        for (int j = 0; j < 8; ++j) acc[i][j] = (f32x4){0.f, 0.f, 0.f, 0.f};

    // A staging: chunk c = tid + i*768 -> sample c>>8, row (c>>2)&63, slot c&3; dest = abuf + c*16
    const char* asrc[4];
    #pragma unroll
    for (int i = 0; i < 4; ++i) {
        int c = tid + i * 768;
        int s = c >> 8, r = (c >> 2) & 63, slot = c & 3;
        int rv = (r < WIN) ? r : (WIN - 1);
        asrc[i] = (const char*)xb + ((size_t)((m * 12 + s) * WIN + rv)) * KB
                + ((slot * 16) ^ (((r >> 1) & 3) << 4));
    }
    // B staging (waves 0..7): chunk tid -> col tid>>2, slot tid&3; dest = bslot + tid*16
    const char* bsrc = (const char*)wt
        + (size_t)(n * BN + (tid >> 2)) * KTOTB
        + (((tid & 3) * 16) ^ ((((tid >> 2) >> 1) & 3) << 4));

    char* const abuf0 = smem;
    char* const abuf1 = smem + ABUF;
    char* const bbase = smem + 2 * ABUF;

    int cbo[8];
    #pragma unroll
    for (int nf = 0; nf < 8; ++nf) {
        int cb = nf * 16 + lr;
        cbo[nf] = cb * 64 + (lq16 ^ (((cb >> 1) & 3) << 4));
    }

    // prologue: A(0) all threads; B(0),B(1),B(2) by waves 0..7
    #pragma unroll
    for (int i = 0; i < 4; ++i)
        GLD16(asrc[i], abuf0 + (tid + i * 768) * 16);
    if (bstager) {
        #pragma unroll
        for (int s = 0; s < 3; ++s)
            GLD16(bsrc + s * KB, bbase + s * BBUF + tid * 16);
    }
    vmwait<0>();
    __builtin_amdgcn_s_barrier();

    int bcur = 0;

#define STEP(KK, W07, W811, TAIL) do {                                             \
    const char* bb = bbase + bcur * BBUF;                                          \
    short8 afr[3];                                                                 \
    _Pragma("unroll")                                                              \
    for (int o = 0; o < 3; ++o) {                                                  \
        int row = o * 16 + lr + (KK);                                              \
        afr[o] = *(const short8*)(awave + row * 64 + (lq16 ^ (((row >> 1) & 3) << 4))); \
    }                                                                              \
    short8 bf[8];                                                                  \
    _Pragma("unroll")                                                              \
    for (int nf = 0; nf < 8; ++nf) bf[nf] = *(const short8*)(bb + cbo[nf]);        \
    if ((!(TAIL) || (KK) < KW - 3) && bstager) {  /* stage B(st+3) */              \
        constexpr int K3 = ((KK) + 3 < KW) ? (KK) + 3 : (KK) + 3 - KW;             \
        int boff = K3 * KB + (((KK) + 3 < KW) ? ci : ci + 1) * 64;                 \
        GLD16(bsrc + boff, bbase + ((bcur + 3) & 3) * BBUF + tid * 16);            \
    }                                                                              \
    if (!(TAIL) && (KK) < 4)  /* stage A(ci+1), chunk-col i = KK */                \
        GLD16(asrc[KK] + (size_t)(ci + 1) * 64, abn + (tid + (KK) * 768) * 16);    \
    __builtin_amdgcn_s_setprio(1);                                                 \
    _Pragma("unroll")                                                              \
    for (int nf = 0; nf < 8; ++nf)                                                 \
        _Pragma("unroll")                                                          \
        for (int o = 0; o < 3; ++o)                                                \
            acc[o][nf] = __builtin_amdgcn_mfma_f32_16x16x32_bf16(afr[o], bf[nf], acc[o][nf], 0, 0, 0); \
    __builtin_amdgcn_s_setprio(0);                                                 \
    if (bstager) vmwait<W07>(); else vmwait<W811>();                               \
    asm volatile("" ::: "memory");                                                 \
    __builtin_amdgcn_s_barrier();                                                  \
    bcur = (bcur + 1) & 3;                                                         \
} while (0)

    for (int ci = 0; ci < CCH - 1; ++ci) {
        const char* ab = (ci & 1) ? abuf1 : abuf0;
        char* abn = (ci & 1) ? abuf0 : abuf1;
        const char* awave = ab + wid * 4096;
        STEP(0, 3, 1, false); STEP(1, 4, 2, false); STEP(2, 4, 2, false);
        STEP(3, 4, 2, false); STEP(4, 3, 1, false); STEP(5, 2, 0, false);
        STEP(6, 2, 0, false); STEP(7, 2, 0, false); STEP(8, 2, 0, false);
        STEP(9, 2, 0, false);
    }
    {   // tail chunk: no A staging; B stages only while KK < 7
        const int ci = CCH - 1;
        const char* ab = (ci & 1) ? abuf1 : abuf0;
        char* abn = (ci & 1) ? abuf0 : abuf1; (void)abn;
        const char* awave = ab + wid * 4096;
        STEP(0, 2, 0, true); STEP(1, 2, 0, true); STEP(2, 2, 0, true);
        STEP(3, 2, 0, true); STEP(4, 2, 0, true); STEP(5, 2, 0, true);
        STEP(6, 2, 0, true); STEP(7, 1, 0, true); STEP(8, 0, 0, true);
        STEP(9, 0, 0, true);
    }
#undef STEP

    // ---- maxpool via shuffles (no LDS) ----
    const int bt = m * 12 + wid;
    #pragma unroll
    for (int nf = 0; nf < 8; ++nf) {
        float mx = -INFINITY;
        #pragma unroll
        for (int o = 0; o < 3; ++o) {
            int rb = o * 16 + lq * 4;
            #pragma unroll
            for (int j = 0; j < 4; ++j)
                if (rb + j < LOUT) mx = fmaxf(mx, acc[o][nf][j]);
        }
        mx = fmaxf(mx, __shfl_xor(mx, 16, 64));
        mx = fmaxf(mx, __shfl_xor(mx, 32, 64));
        if (lane < 16) {
            int col = n * BN + nf * 16 + lane;
            pooled[(size_t)bt * COUT + col] = mx + bias[col];
        }
    }
}

// ================= conv1d GEMM v10 (kept for L and E): per-step barrier, counted vmcnt =================
template<int LOUT, int WIN, int CINP, int KW, int BN, int NS, int MFR, int COUT>
__global__ __launch_bounds__(256, 2)
void conv_pool_v10(const unsigned short* __restrict__ xb, const unsigned short* __restrict__ wt,
                   const float* __restrict__ bias, float* __restrict__ pooled)
{
    constexpr int CCH   = CINP / 32;
    constexpr int KB    = CINP * 2;
    constexpr int KTOTB = CINP * KW * 2;
    constexpr int NFR   = BN / 16;
    constexpr int B_IT  = BN / 64;
    constexpr int ABUF  = 4 * 64 * 64;
    constexpr int BBUF  = BN * 64;
    constexpr int CPQ   = (BTOT / 4) / 4;

    __shared__ __align__(16) char smem[2 * ABUF + 4 * BBUF];

    const int tid  = threadIdx.x;
    const int lane = tid & 63;
    const int wid  = tid >> 6;
    const int lr   = lane & 15;
    const int lq   = lane >> 4;
    const int lq16 = lq * 16;

    int m, n;
    if constexpr (NS == 2) {
        int xcd = blockIdx.x & 7;
        n = xcd & 1;
        m = (xcd >> 1) * CPQ + (blockIdx.x >> 3);
    } else {
        m = blockIdx.x; n = 0;
    }

    f32x4 acc[MFR][NFR];
    #pragma unroll
    for (int i = 0; i < MFR; ++i)
        #pragma unroll
        for (int j = 0; j < NFR; ++j) acc[i][j] = (f32x4){0.f, 0.f, 0.f, 0.f};

    const int aw_r = tid >> 2;
    const int aw   = (aw_r < WIN) ? aw_r : (WIN - 1);
    const int slot = tid & 3;
    const char* asrc[4];
    #pragma unroll
    for (int i = 0; i < 4; ++i)
        asrc[i] = (const char*)xb + ((size_t)((m * 4 + i) * WIN + aw)) * KB
                + ((slot * 16) ^ (((aw_r >> 1) & 3) << 4));
    const char* bsrc[B_IT];
    #pragma unroll
    for (int i = 0; i < B_IT; ++i) {
        int col = (tid + i * 256) >> 2;
        bsrc[i] = (const char*)wt + (size_t)(n * BN + col) * KTOTB
                + ((slot * 16) ^ (((col >> 1) & 3) << 4));
    }

    char* const abuf0 = smem;
    char* const abuf1 = smem + ABUF;
    char* const bbase = smem + 2 * ABUF;

    int cbo[NFR];
    #pragma unroll
    for (int nf = 0; nf < NFR; ++nf) {
        int cb = nf * 16 + lr;
        cbo[nf] = cb * 64 + (lq16 ^ (((cb >> 1) & 3) << 4));
    }

    #pragma unroll
    for (int i = 0; i < 4; ++i)
        GLD16(asrc[i], abuf0 + i * 4096 + tid * 16);
    #pragma unroll
    for (int s = 0; s < 3; ++s)
        #pragma unroll
        for (int i = 0; i < B_IT; ++i)
            GLD16(bsrc[i] + s * KB, bbase + s * BBUF + i * 4096 + tid * 16);
    vmwait<0>();
    __builtin_amdgcn_s_barrier();

    int bcur = 0;

#define STEP(KK, WN, TAIL) do {                                                    \
    const char* bb = bbase + bcur * BBUF;                                          \
    short8 afr[MFR];                                                               \
    _Pragma("unroll")                                                              \
    for (int o = 0; o < MFR; ++o) {                                                \
        int row = o * 16 + lr + (KK);                                              \
        afr[o] = *(const short8*)(awave + row * 64 + (lq16 ^ (((row >> 1) & 3) << 4))); \
    }                                                                              \
    short8 bf[NFR];                                                                \
    _Pragma("unroll")                                                              \
    for (int nf = 0; nf < NFR; ++nf) bf[nf] = *(const short8*)(bb + cbo[nf]);      \
    if (!(TAIL) || (KK) < KW - 3) {                                                \
        constexpr int k3_ = ((KK) + 3 < KW) ? (KK) + 3 : (KK) + 3 - KW;            \
        int boff = k3_ * KB + (((KK) + 3 < KW) ? ci : ci + 1) * 64;                \
        char* bstg = bbase + ((bcur + 3) & 3) * BBUF;                              \
        _Pragma("unroll")                                                          \
        for (int i = 0; i < B_IT; ++i)                                             \
            GLD16(bsrc[i] + boff, bstg + i * 4096 + tid * 16);                     \
    }                                                                              \
    if (!(TAIL)) {                                                                 \
        if (KW >= 8) {                                                             \
            if ((KK) < 4)                                                          \
                GLD16(asrc[(KK) & 3] + (size_t)(ci + 1) * 64, abn + ((KK) & 3) * 4096 + tid * 16); \
        } else if ((KK) == 0) {                                                    \
            _Pragma("unroll")                                                      \
            for (int i = 0; i < 4; ++i)                                            \
                GLD16(asrc[i] + (size_t)(ci + 1) * 64, abn + i * 4096 + tid * 16); \
        }                                                                          \
    }                                                                              \
    __builtin_amdgcn_s_setprio(1);                                                 \
    _Pragma("unroll")                                                              \
    for (int nf = 0; nf < NFR; ++nf)                                               \
        _Pragma("unroll")                                                          \
        for (int o = 0; o < MFR; ++o)                                              \
            acc[o][nf] = __builtin_amdgcn_mfma_f32_16x16x32_bf16(afr[o], bf[nf], acc[o][nf], 0, 0, 0); \
    __builtin_amdgcn_s_setprio(0);                                                 \
    vmwait<WN>();                                                                  \
    asm volatile("" ::: "memory");                                                 \
    __builtin_amdgcn_s_barrier();                                                  \
    bcur = (bcur + 1) & 3;                                                         \
} while (0)

    for (int ci = 0; ci < CCH - 1; ++ci) {
        const char* ab = (ci & 1) ? abuf1 : abuf0;
        char* abn = (ci & 1) ? abuf0 : abuf1;
        const char* awave = ab + wid * 4096;
        if constexpr (KW == 5) {
            STEP(0, 8, false); STEP(1, 8, false); STEP(2, 4, false); STEP(3, 4, false); STEP(4, 4, false);
        } else {
            STEP(0, 6, false); STEP(1, 6, false); STEP(2, 2, false);
        }
    }
    {
        const int ci = CCH - 1;
        const char* ab = (ci & 1) ? abuf1 : abuf0;
        char* abn = (ci & 1) ? abuf0 : abuf1; (void)abn;
        const char* awave = ab + wid * 4096;
        if constexpr (KW == 5) {
            STEP(0, 4, true); STEP(1, 4, true); STEP(2, 2, true); STEP(3, 0, true); STEP(4, 0, true);
        } else {
            STEP(0, 1, true); STEP(1, 0, true); STEP(2, 0, true);
        }
    }
#undef STEP

    const int bt = m * 4 + wid;
    #pragma unroll
    for (int nf = 0; nf < NFR; ++nf) {
        float mx = -INFINITY;
        #pragma unroll
        for (int o = 0; o < MFR; ++o) {
            int rb = o * 16 + lq * 4;
            #pragma unroll
            for (int j = 0; j < 4; ++j)
                if (rb + j < LOUT) mx = fmaxf(mx, acc[o][nf][j]);
        }
        mx = fmaxf(mx, __shfl_xor(mx, 16, 64));
        mx = fmaxf(mx, __shfl_xor(mx, 32, 64));
        if (lane < 16) {
            int col = n * BN + nf * 16 + lane;
            pooled[(size_t)bt * COUT + col] = mx + bias[col];
        }
    }
}

// ---------------- fused highway v2: sample-batched (A:8/blk, L:16/blk, E:32/blk) ----------------
#define HWA_BLOCKS 192
#define HWL_BLOCKS 96
#define HWE_BLOCKS 48
__global__ __launch_bounds__(256)
void highway_v2(const float* __restrict__ pL, const float* __restrict__ pA, const float* __restrict__ pE,
                const float* __restrict__ WpTL, const float* __restrict__ bpL,
                const float* __restrict__ WgTL, const float* __restrict__ bgL,
                const float* __restrict__ WpTA, const float* __restrict__ bpA,
                const float* __restrict__ WgTA, const float* __restrict__ bgA,
                const float* __restrict__ WpTE, const float* __restrict__ bpE,
                const float* __restrict__ WgTE, const float* __restrict__ bgE,
                float* __restrict__ out) {
    __shared__ float xs[2048];
    int bx = blockIdx.x;
    int tid = threadIdx.x;
    if (bx < HWA_BLOCKS) {                      // acoustic: 8 samples x 256 cols
        int bt0 = bx * 8;
        #pragma unroll
        for (int s = 0; s < 8; ++s) xs[s * 256 + tid] = pA[(size_t)(bt0 + s) * 256 + tid];
        __syncthreads();
        float p[8], g[8];
        #pragma unroll
        for (int s = 0; s < 8; ++s) { p[s] = bpA[tid]; g[s] = bgA[tid]; }
        for (int c = 0; c < 256; ++c) {
            float wp = WpTA[c * 256 + tid], wg = WgTA[c * 256 + tid];
            #pragma unroll
            for (int s = 0; s < 8; ++s) {
                float xv = xs[s * 256 + c];
                p[s] += xv * wp; g[s] += xv * wg;
            }
        }
        #pragma unroll
        for (int s = 0; s < 8; ++s) {
            float pp = fmaxf(p[s], 0.f);
            float gg = sigmf(g[s]);
            out[(size_t)(bt0 + s) * 448 + 128 + tid] = gg * pp + (1.f - gg) * xs[s * 256 + tid];
        }
    } else if (bx < HWA_BLOCKS + HWL_BLOCKS) {  // linguistic: 16 samples x 128 cols
        int bt0 = (bx - HWA_BLOCKS) * 16;
        for (int i = tid; i < 16 * 128; i += 256) xs[i] = pL[(size_t)bt0 * 128 + i];
        __syncthreads();
        int j = tid & 127, h = tid >> 7;
        float p[8], g[8];
        #pragma unroll
        for (int s = 0; s < 8; ++s) { p[s] = bpL[j]; g[s] = bgL[j]; }
        for (int c = 0; c < 128; ++c) {
            float wp = WpTL[c * 128 + j], wg = WgTL[c * 128 + j];
            #pragma unroll
            for (int s = 0; s < 8; ++s) {
                float xv = xs[(h * 8 + s) * 128 + c];
                p[s] += xv * wp; g[s] += xv * wg;
            }
        }
        #pragma unroll
        for (int s = 0; s < 8; ++s) {
            float pp = fmaxf(p[s], 0.f);
            float gg = sigmf(g[s]);
            out[(size_t)(bt0 + h * 8 + s) * 448 + j] = gg * pp + (1.f - gg) * xs[(h * 8 + s) * 128 + j];
        }
    } else {                                    // emotient: 32 samples x 64 cols
        int bt0 = (bx - HWA_BLOCKS - HWL_BLOCKS) * 32;
        for (int i = tid; i < 32 * 64; i += 256) xs[i] = pE[(size_t)bt0 * 64 + i];
        __syncthreads();
        int j = tid & 63, grp = tid >> 6;
        float p[8], g[8];
        #pragma unroll
        for (int s = 0; s < 8; ++s) { p[s] = bpE[j]; g[s] = bgE[j]; }
        for (int c = 0; c < 64; ++c) {
            float wp = WpTE[c * 64 + j], wg = WgTE[c * 64 + j];
            #pragma unroll
            for (int s = 0; s < 8; ++s) {
                float xv = xs[(grp * 8 + s) * 64 + c];
                p[s] += xv * wp; g[s] += xv * wg;
            }
        }
        #pragma unroll
        for (int s = 0; s < 8; ++s) {
            float pp = fmaxf(p[s], 0.f);
            float gg = sigmf(g[s]);
            out[(size_t)(bt0 + grp * 8 + s) * 448 + 384 + j] = gg * pp + (1.f - gg) * xs[(grp * 8 + s) * 64 + j];
        }
    }
}

// ================= fallback path (tiny workspace): slow but correct =================
__global__ __launch_bounds__(512)
void lstm_kernel_f32(const float* __restrict__ x, const int* __restrict__ lens,
                     const float* __restrict__ WihT, const float* __restrict__ WhhT,
                     const float* __restrict__ bih, const float* __restrict__ bhh,
                     float* __restrict__ hout) {
    int bt = blockIdx.x;
    int j  = threadIdx.x;
    __shared__ float xs[WE_][EE];
    __shared__ __align__(16) float hs[HH];
    __shared__ float zs[512];
    for (int idx = j; idx < WE_ * EE; idx += 512)
        ((float*)xs)[idx] = x[(size_t)bt * WE_ * EE + idx];
    if (j < HH) hs[j] = 0.f;
    float wih[EE];
    #pragma unroll
    for (int e = 0; e < EE; ++e) wih[e] = WihT[e * 512 + j];
    float whh[HH];
    #pragma unroll
    for (int h = 0; h < HH; ++h) whh[h] = WhhT[h * 512 + j];
    float bjv = bih[j] + bhh[j];
    float c_reg = 0.f;
    int len = lens[bt];
    __syncthreads();
    for (int t = 0; t < WE_; ++t) {
        float z = bjv;
        #pragma unroll
        for (int e = 0; e < EE; ++e) z += wih[e] * xs[t][e];
        const float4* h4 = (const float4*)hs;
        #pragma unroll
        for (int q = 0; q < HH / 4; ++q) {
            float4 hv = h4[q];
            z += whh[4*q+0] * hv.x + whh[4*q+1] * hv.y
               + whh[4*q+2] * hv.z + whh[4*q+3] * hv.w;
        }
        zs[j] = z;
        __syncthreads();
        if (j < HH) {
            float zi = zs[j], zf = zs[HH + j], zg = zs[2*HH + j], zo = zs[3*HH + j];
            float si = 1.f / (1.f + expf(-zi));
            float sf = 1.f / (1.f + expf(-zf));
            float so = 1.f / (1.f + expf(-zo));
            float tg = tanhf(zg);
            float c2 = sf * c_reg + si * tg;
            float h2 = so * tanhf(c2);
            bool valid = (t < len);
            float hn = valid ? h2 : hs[j];
            c_reg    = valid ? c2 : c_reg;
            hout[((size_t)bt * WE_ + t) * HH + j] = valid ? h2 : 0.f;
            hs[j] = hn;
        }
        __syncthreads();
    }
}

template<int CIN, int WIN, int COUT, int KDIM, int LOUT>
__global__ __launch_bounds__(256)
void conv_pool_simple(const float* __restrict__ x, const float* __restrict__ w,
                      const float* __restrict__ bias, float* __restrict__ pooled)
{
    constexpr int KW = KDIM / CIN;
    int bt = blockIdx.x;
    int co = blockIdx.y * 64 + (threadIdx.x & 63);
    int seg = threadIdx.x >> 6;
    __shared__ float part[4][64];
    float m = -INFINITY;
    for (int l = seg; l < LOUT; l += 4) {
        float acc = 0.f;
        for (int k = 0; k < KW; ++k) {
            const float* xr = x + ((size_t)bt * WIN + l + k) * CIN;
            const float* wr = w + ((size_t)co * CIN) * KW + k;
            for (int cc = 0; cc < CIN; ++cc) acc += xr[cc] * wr[(size_t)cc * KW];
        }
        m = fmaxf(m, acc);
    }
    part[seg][threadIdx.x & 63] = m;
    __syncthreads();
    if (threadIdx.x < 64) {
        float mm = fmaxf(fmaxf(part[0][threadIdx.x], part[1][threadIdx.x]),
                         fmaxf(part[2][threadIdx.x], part[3][threadIdx.x]));
        pooled[(size_t)bt * COUT + co] = mm + bias[co];
    }
}

// ---------------- launch ----------------
static inline int cdiv(int a, int b) { return (a + b - 1) / b; }

extern "C" void kernel_launch(void* const* d_in, const int* in_sizes, int n_in,
                              void* d_out, int out_size, void* d_ws, size_t ws_size,
                              hipStream_t stream) {
    const float* x_lin  = (const float*)d_in[0];
    const float* x_aco  = (const float*)d_in[1];
    const float* x_emo  = (const float*)d_in[2];
    const int*   wlen   = (const int*)  d_in[3];
    const float* convL_w = (const float*)d_in[5];
    const float* convL_b = (const float*)d_in[6];
    const float* convA_w = (const float*)d_in[7];
    const float* convA_b = (const float*)d_in[8];
    const float* convE_w = (const float*)d_in[9];
    const float* convE_b = (const float*)d_in[10];
    const float* hwL_Wp = (const float*)d_in[11];
    const float* hwL_bp = (const float*)d_in[12];
    const float* hwL_Wg = (const float*)d_in[13];
    const float* hwL_bg = (const float*)d_in[14];
    const float* hwA_Wp = (const float*)d_in[15];
    const float* hwA_bp = (const float*)d_in[16];
    const float* hwA_Wg = (const float*)d_in[17];
    const float* hwA_bg = (const float*)d_in[18];
    const float* hwE_Wp = (const float*)d_in[19];
    const float* hwE_bp = (const float*)d_in[20];
    const float* hwE_Wg = (const float*)d_in[21];
    const float* hwE_bg = (const float*)d_in[22];
    const float* lstm_Wih = (const float*)d_in[23];
    const float* lstm_Whh = (const float*)d_in[24];
    const float* lstm_bih = (const float*)d_in[25];
    const float* lstm_bhh = (const float*)d_in[26];
    float* out = (float*)d_out;

    // ---- workspace carve (256B aligned) ----
    char* p0 = (char*)d_ws;
    char* p = p0;
    auto alloc = [&](size_t bytes) { char* r = p; p += (bytes + 255) & ~(size_t)255; return r; };
    float* WpTL = (float*)alloc((size_t)CL * CL * 4);
    float* WgTL = (float*)alloc((size_t)CL * CL * 4);
    float* WpTA = (float*)alloc((size_t)CA * CA * 4);
    float* WgTA = (float*)alloc((size_t)CA * CA * 4);
    float* WpTE = (float*)alloc((size_t)CE * CE * 4);
    float* WgTE = (float*)alloc((size_t)CE * CE * 4);
    float* WihT = (float*)alloc((size_t)EE * 512 * 4);
    float* WhhT = (float*)alloc((size_t)HH * 512 * 4);
    unsigned short* whh_bf  = (unsigned short*)alloc((size_t)512 * 128 * 2);
    unsigned short* wihp_bf = (unsigned short*)alloc((size_t)512 * 32 * 2);
    void*  hbuf = (void*)alloc((size_t)BTOT * WE_ * HH * 4);
    float* pL   = (float*)alloc((size_t)BTOT * CL * 4);
    float* pA   = (float*)alloc((size_t)BTOT * CA * 4);
    float* pE   = (float*)alloc((size_t)BTOT * CE * 4);
    unsigned short* wtA = (unsigned short*)alloc((size_t)CA * KPA * 2);
    unsigned short* wtL = (unsigned short*)alloc((size_t)CL * KPL * 2);
    unsigned short* wtE = (unsigned short*)alloc((size_t)CE * KPE * 2);
    unsigned short* xlin_p = (unsigned short*)alloc((size_t)BTOT * WL_ * ELP * 2 + 64);
    unsigned short* xaco_p = (unsigned short*)alloc((size_t)BTOT * WA_ * EAP * 2 + 64);
    size_t need = (size_t)(p - p0);
    bool big = ws_size >= need;

    if (big) {
        prep_all<true><<<2048, 256, 0, stream>>>(hwL_Wp, WpTL, hwL_Wg, WgTL, hwA_Wp, WpTA, hwA_Wg, WgTA,
                                                 hwE_Wp, WpTE, hwE_Wg, WgTE, lstm_Wih, WihT, lstm_Whh, WhhT,
                                                 convL_w, wtL, convE_w, wtE, convA_w, wtA, whh_bf, wihp_bf);
        lstm_cvt<<<LSTM_BLOCKS + CVT_BLOCKS, 512, 0, stream>>>(
            x_emo, wihp_bf, whh_bf, lstm_bih, lstm_bhh, wlen, (unsigned short*)hbuf,
            x_aco, x_lin, xaco_p, xlin_p);
        conv_a12<<<CONVA12_BLOCKS, 768, 0, stream>>>(xaco_p, wtA, convA_b, pA);
        conv_pool_v10<LOUTL, WL_, ELP, 5, 128, 1, 2, CL>
            <<<384, 256, 0, stream>>>(xlin_p, wtL, convL_b, pL);
        conv_pool_v10<LOUTE, WE_, HH, 3, 64, 1, 2, CE>
            <<<384, 256, 0, stream>>>((const unsigned short*)hbuf, wtE, convE_b, pE);
        highway_v2<<<HWA_BLOCKS + HWL_BLOCKS + HWE_BLOCKS, 256, 0, stream>>>(
            pL, pA, pE, WpTL, hwL_bp, WgTL, hwL_bg, WpTA, hwA_bp, WgTA, hwA_bg,
            WpTE, hwE_bp, WgTE, hwE_bg, out);
    } else {
        prep_all<false><<<2048, 256, 0, stream>>>(hwL_Wp, WpTL, hwL_Wg, WgTL, hwA_Wp, WpTA, hwA_Wg, WgTA,
                                                  hwE_Wp, WpTE, hwE_Wg, WgTE, lstm_Wih, WihT, lstm_Whh, WhhT,
                                                  convL_w, wtL, convE_w, wtE, convA_w, wtA, whh_bf, wihp_bf);
        lstm_kernel_f32<<<BTOT, 512, 0, stream>>>(x_emo, wlen, WihT, WhhT, lstm_bih, lstm_bhh, (float*)hbuf);
        conv_pool_simple<EA, WA_, CA, KDIMA, LOUTA>
            <<<dim3(BTOT, CA / 64), 256, 0, stream>>>(x_aco, convA_w, convA_b, pA);
        conv_pool_simple<EL, WL_, CL, KDIML, LOUTL>
            <<<dim3(BTOT, CL / 64), 256, 0, stream>>>(x_lin, convL_w, convL_b, pL);
        conv_pool_simple<HH, WE_, CE, KDIME, LOUTE>
            <<<dim3(BTOT, CE / 64), 256, 0, stream>>>((const float*)hbuf, convE_w, convE_b, pE);
        highway_v2<<<HWA_BLOCKS + HWL_BLOCKS + HWE_BLOCKS, 256, 0, stream>>>(
            pL, pA, pE, WpTL, hwL_bp, WgTL, hwL_bg, WpTA, hwA_bp, WgTA, hwA_bg,
            WpTE, hwE_bp, WgTE, hwE_bg, out);
    }
}

// Round 13
// 537.952 us; speedup vs baseline: 1.6169x; 1.6169x over previous
//
#include <hip/hip_runtime.h>
#include <hip/hip_bf16.h>
#include <math.h>

// ---------------- problem dims (fixed by setup_inputs) ----------------
#define BTOT 1536            // B*T = 32*48
// linguistic
#define EL 300
#define ELP 320              // padded CIN (10 c-chunks of 32)
#define WL_ 33
#define CL 128
#define LOUTL 29
#define KPL 1600
// acoustic
#define EA 988
#define EAP 992              // 31 c-chunks
#define WA_ 50
#define CA 256
#define LOUTA 41
#define KPA 9920
// emotient
#define EE 20
#define WE_ 30
#define HH 128
#define CE 64
#define LOUTE 28
#define KPE 384
// fallback K dims
#define KDIML 1500
#define KDIMA 9880
#define KDIME 384

typedef __attribute__((ext_vector_type(4))) float f32x4;
typedef __attribute__((ext_vector_type(8))) short short8;

// RNE float->bf16 (inputs finite)
__device__ __forceinline__ unsigned short f2bf(float f) {
    unsigned int x = __float_as_uint(f);
    unsigned int r = (x + 0x7fffu + ((x >> 16) & 1u)) >> 16;
    return (unsigned short)r;
}

__device__ __forceinline__ float sigmf(float x) {
    return __builtin_amdgcn_rcpf(1.f + __expf(-x));
}
__device__ __forceinline__ float tanh_fast(float x) {
    return 1.f - 2.f * __builtin_amdgcn_rcpf(1.f + __expf(2.f * x));
}

#define GLD16(gp, lp) __builtin_amdgcn_global_load_lds( \
    (const __attribute__((address_space(1))) void*)(gp), \
    (__attribute__((address_space(3))) void*)(lp), 16, 0, 0)

template<int N> __device__ __forceinline__ void vmwait() {
    if constexpr (N == 0) asm volatile("s_waitcnt vmcnt(0)" ::: "memory");
    else if constexpr (N == 1) asm volatile("s_waitcnt vmcnt(1)" ::: "memory");
    else if constexpr (N == 2) asm volatile("s_waitcnt vmcnt(2)" ::: "memory");
    else if constexpr (N == 3) asm volatile("s_waitcnt vmcnt(3)" ::: "memory");
    else if constexpr (N == 4) asm volatile("s_waitcnt vmcnt(4)" ::: "memory");
    else if constexpr (N == 6) asm volatile("s_waitcnt vmcnt(6)" ::: "memory");
    else if constexpr (N == 8) asm volatile("s_waitcnt vmcnt(8)" ::: "memory");
    else static_assert(N == 0, "add case");
}

// ---------------- small helpers ----------------
__device__ __forceinline__ void tr_one(const float* a, float* at, int R, int C, int idx) {
    int r = idx / C, c = idx - r * C;
    at[c * R + r] = a[idx];
}
template<int CIN, int CINP, int KW, int COUT, int KPAD>
__device__ __forceinline__ void wt_one(const float* w, unsigned short* wt, int idx) {
    int co = idx / KPAD;
    int p  = idx - co * KPAD;
    int k  = p / CINP;
    int c  = p - k * CINP;
    float v = 0.f;
    if (k < KW && c < CIN) v = w[(co * CIN + c) * KW + k];
    wt[idx] = f2bf(v);
}
template<int CIN, int CINP>
__device__ __forceinline__ void cvt_chunk(const float* in, unsigned short* out, int idx) {
    constexpr int CH = CINP / 8;
    int row = idx / CH, c0 = (idx - row * CH) * 8;
    const float* src = in + (size_t)row * CIN + c0;
    union { short8 s; unsigned short u[8]; } o;
    if (c0 + 8 <= CIN) {
        float4 v0 = *(const float4*)src;
        float4 v1 = *(const float4*)(src + 4);
        o.u[0]=f2bf(v0.x); o.u[1]=f2bf(v0.y); o.u[2]=f2bf(v0.z); o.u[3]=f2bf(v0.w);
        o.u[4]=f2bf(v1.x); o.u[5]=f2bf(v1.y); o.u[6]=f2bf(v1.z); o.u[7]=f2bf(v1.w);
    } else {
        #pragma unroll
        for (int j = 0; j < 8; ++j) o.u[j] = (c0 + j < CIN) ? f2bf(src[j]) : (unsigned short)0;
    }
    *(short8*)(out + (size_t)row * CINP + c0) = o.s;
}

// ================= fused LSTM + cvtA + cvtL + all weight prep, one launch =================
// blocks [0,96): LSTM (reads raw f32 weights, converts in-kernel).
// blocks [96, 96+1952): grid-stride over {cvtA, cvtL, highway transposes, wtL, wtE, wtA}.
#define LSTM_BLOCKS 96
#define AUX_BLOCKS 1952

__global__ __launch_bounds__(512, 1)
void lstm_cvt_prep(const float* __restrict__ x_emo,
                   const float* __restrict__ lstm_Wih, const float* __restrict__ lstm_Whh,
                   const float* __restrict__ bih, const float* __restrict__ bhh,
                   const int* __restrict__ lens, unsigned short* __restrict__ hbuf,
                   const float* __restrict__ xa, const float* __restrict__ xl,
                   unsigned short* __restrict__ outa, unsigned short* __restrict__ outl,
                   const float* hwL_Wp, float* WpTL, const float* hwL_Wg, float* WgTL,
                   const float* hwA_Wp, float* WpTA, const float* hwA_Wg, float* WgTA,
                   const float* hwE_Wp, float* WpTE, const float* hwE_Wg, float* WgTE,
                   const float* convL_w, unsigned short* wtL,
                   const float* convE_w, unsigned short* wtE,
                   const float* convA_w, unsigned short* wtA)
{
    __shared__ __align__(16) unsigned short xq[WE_ * 16 * 32];  // 30 KB
    __shared__ __align__(16) char h_s[2 * 16 * HH * 2];         // 8 KB dbuf, swizzled

    if (blockIdx.x >= LSTM_BLOCKS) {
        constexpr int NAC = (BTOT * WA_) * (EAP / 8);
        constexpr int NLC = (BTOT * WL_) * (ELP / 8);
        constexpr int S1 = 16384, S2 = 16384, S3 = 65536, S4 = 65536, S5 = 4096, S6 = 4096;
        constexpr int S9 = 128 * KPL, S10 = 64 * KPE, S13 = CA * KPA;
        constexpr int TOTAL = NAC + NLC + S1 + S2 + S3 + S4 + S5 + S6 + S9 + S10 + S13;
        int stride = AUX_BLOCKS * 512;
        for (int i = (blockIdx.x - LSTM_BLOCKS) * 512 + threadIdx.x; i < TOTAL; i += stride) {
            int idx = i;
            if (idx < NAC) { cvt_chunk<EA, EAP>(xa, outa, idx); continue; } idx -= NAC;
            if (idx < NLC) { cvt_chunk<EL, ELP>(xl, outl, idx); continue; } idx -= NLC;
            if (idx < S1) { tr_one(hwL_Wp, WpTL, 128, 128, idx); continue; } idx -= S1;
            if (idx < S2) { tr_one(hwL_Wg, WgTL, 128, 128, idx); continue; } idx -= S2;
            if (idx < S3) { tr_one(hwA_Wp, WpTA, 256, 256, idx); continue; } idx -= S3;
            if (idx < S4) { tr_one(hwA_Wg, WgTA, 256, 256, idx); continue; } idx -= S4;
            if (idx < S5) { tr_one(hwE_Wp, WpTE, 64, 64, idx); continue; } idx -= S5;
            if (idx < S6) { tr_one(hwE_Wg, WgTE, 64, 64, idx); continue; } idx -= S6;
            if (idx < S9) { wt_one<EL, ELP, 5, CL, KPL>(convL_w, wtL, idx); continue; } idx -= S9;
            if (idx < S10) { wt_one<HH, HH, 3, CE, KPE>(convE_w, wtE, idx); continue; } idx -= S10;
            wt_one<EA, EAP, 10, CA, KPA>(convA_w, wtA, idx);
        }
        return;
    }

    // ---- LSTM path: 16 samples/block; weights converted from raw f32 in-kernel ----
    const int tid  = threadIdx.x;
    const int w    = tid >> 6;
    const int lane = tid & 63;
    const int lr   = lane & 15;
    const int lq   = lane >> 4;
    const int s0   = blockIdx.x * 16;
    const int c    = w * 16 + lr;     // gate-col within 128

    short8 bfr[4][4];
    short8 bw[4];
    float bj[4];
    #pragma unroll
    for (int g = 0; g < 4; ++g) {
        int col = g * 128 + c;
        #pragma unroll
        for (int kt = 0; kt < 4; ++kt) {
            const float* s = lstm_Whh + (size_t)col * 128 + kt * 32 + lq * 8;
            float4 v0 = *(const float4*)s;
            float4 v1 = *(const float4*)(s + 4);
            union { short8 sv; unsigned short u[8]; } o;
            o.u[0]=f2bf(v0.x); o.u[1]=f2bf(v0.y); o.u[2]=f2bf(v0.z); o.u[3]=f2bf(v0.w);
            o.u[4]=f2bf(v1.x); o.u[5]=f2bf(v1.y); o.u[6]=f2bf(v1.z); o.u[7]=f2bf(v1.w);
            bfr[g][kt] = o.sv;
        }
        union { short8 sv; unsigned short u[8]; } ow;
        #pragma unroll
        for (int j = 0; j < 8; ++j) {
            int e = lq * 8 + j;
            ow.u[j] = (e < 20) ? f2bf(lstm_Wih[(size_t)col * 20 + e]) : (unsigned short)0;
        }
        bw[g] = ow.sv;
        bj[g] = bih[col] + bhh[col];
    }
    int len4[4];
    #pragma unroll
    for (int j = 0; j < 4; ++j) len4[j] = lens[s0 + lq * 4 + j];

    for (int i = tid; i < WE_ * 16 * 32; i += 512) {
        int t = i >> 9, r = (i >> 5) & 15, e = i & 31;
        xq[i] = (e < 20) ? f2bf(x_emo[(((size_t)(s0 + r) * WE_) + t) * 20 + e]) : (unsigned short)0;
    }
    for (int i = tid; i < 2048; i += 512) ((unsigned int*)h_s)[i] = 0u;

    float c_prev[4] = {0.f, 0.f, 0.f, 0.f};
    unsigned short hb_prev[4] = {0, 0, 0, 0};
    __syncthreads();

    for (int t = 0; t < WE_; ++t) {
        const char* hsr = h_s + (t & 1) * 4096;
        char* hsw = h_s + ((t & 1) ^ 1) * 4096;
        short8 ax = *(const short8*)((const char*)xq + (size_t)(t * 16 + lr) * 64 + lq * 16);
        short8 af[4];
        #pragma unroll
        for (int kt = 0; kt < 4; ++kt)
            af[kt] = *(const short8*)(hsr + ((lr * 256 + kt * 64 + lq * 16) ^ ((lr & 7) << 4)));
        f32x4 acc[4];
        #pragma unroll
        for (int g = 0; g < 4; ++g)
            acc[g] = __builtin_amdgcn_mfma_f32_16x16x32_bf16(ax, bw[g], (f32x4){0.f,0.f,0.f,0.f}, 0, 0, 0);
        #pragma unroll
        for (int kt = 0; kt < 4; ++kt)
            #pragma unroll
            for (int g = 0; g < 4; ++g)
                acc[g] = __builtin_amdgcn_mfma_f32_16x16x32_bf16(af[kt], bfr[g][kt], acc[g], 0, 0, 0);
        #pragma unroll
        for (int j = 0; j < 4; ++j) {
            int s = lq * 4 + j;
            float zi = acc[0][j] + bj[0];
            float zf = acc[1][j] + bj[1];
            float zg = acc[2][j] + bj[2];
            float zo = acc[3][j] + bj[3];
            float si = sigmf(zi), sf = sigmf(zf), so = sigmf(zo);
            float tg = tanh_fast(zg);
            float c2 = sf * c_prev[j] + si * tg;
            float h2 = so * tanh_fast(c2);
            bool valid = (t < len4[j]);
            c_prev[j] = valid ? c2 : c_prev[j];
            unsigned short h2b = f2bf(h2);
            unsigned short hn = valid ? h2b : hb_prev[j];
            hb_prev[j] = hn;
            *(unsigned short*)(hsw + (((s * HH + c) * 2) ^ ((s & 7) << 4))) = hn;
            hbuf[(((size_t)(s0 + s) * WE_) + t) * HH + c] = valid ? h2b : (unsigned short)0;
        }
        __syncthreads();
    }
}

// ================= conv bodies (device functions; proven r10/r11 schedules) =================
// v10 body: per-step barrier, 4-slot B ring staged 3 ahead, counted vmcnt (used for L and E).
template<int LOUT, int WIN, int CINP, int KW, int BN, int MFR, int COUT>
__device__ __forceinline__
void conv_body_v10(char* smem, int m, int n,
                   const unsigned short* __restrict__ xb, const unsigned short* __restrict__ wt,
                   const float* __restrict__ bias, float* __restrict__ pooled)
{
    constexpr int CCH   = CINP / 32;
    constexpr int KB    = CINP * 2;
    constexpr int KTOTB = CINP * KW * 2;
    constexpr int NFR   = BN / 16;
    constexpr int B_IT  = BN / 64;
    constexpr int ABUF  = 4 * 64 * 64;
    constexpr int BBUF  = BN * 64;

    const int tid  = threadIdx.x;
    const int lane = tid & 63;
    const int wid  = tid >> 6;
    const int lr   = lane & 15;
    const int lq   = lane >> 4;
    const int lq16 = lq * 16;

    f32x4 acc[MFR][NFR];
    #pragma unroll
    for (int i = 0; i < MFR; ++i)
        #pragma unroll
        for (int j = 0; j < NFR; ++j) acc[i][j] = (f32x4){0.f, 0.f, 0.f, 0.f};

    const int aw_r = tid >> 2;
    const int aw   = (aw_r < WIN) ? aw_r : (WIN - 1);
    const int slot = tid & 3;
    const char* asrc[4];
    #pragma unroll
    for (int i = 0; i < 4; ++i)
        asrc[i] = (const char*)xb + ((size_t)((m * 4 + i) * WIN + aw)) * KB
                + ((slot * 16) ^ (((aw_r >> 1) & 3) << 4));
    const char* bsrc[B_IT];
    #pragma unroll
    for (int i = 0; i < B_IT; ++i) {
        int col = (tid + i * 256) >> 2;
        bsrc[i] = (const char*)wt + (size_t)(n * BN + col) * KTOTB
                + ((slot * 16) ^ (((col >> 1) & 3) << 4));
    }

    char* const abuf0 = smem;
    char* const abuf1 = smem + ABUF;
    char* const bbase = smem + 2 * ABUF;

    int cbo[NFR];
    #pragma unroll
    for (int nf = 0; nf < NFR; ++nf) {
        int cb = nf * 16 + lr;
        cbo[nf] = cb * 64 + (lq16 ^ (((cb >> 1) & 3) << 4));
    }

    #pragma unroll
    for (int i = 0; i < 4; ++i)
        GLD16(asrc[i], abuf0 + i * 4096 + tid * 16);
    #pragma unroll
    for (int s = 0; s < 3; ++s)
        #pragma unroll
        for (int i = 0; i < B_IT; ++i)
            GLD16(bsrc[i] + s * KB, bbase + s * BBUF + i * 4096 + tid * 16);
    vmwait<0>();
    __builtin_amdgcn_s_barrier();

    int bcur = 0;

#define STEP(KK, WN, TAIL) do {                                                    \
    const char* bb = bbase + bcur * BBUF;                                          \
    short8 afr[MFR];                                                               \
    _Pragma("unroll")                                                              \
    for (int o = 0; o < MFR; ++o) {                                                \
        int row = o * 16 + lr + (KK);                                              \
        afr[o] = *(const short8*)(awave + row * 64 + (lq16 ^ (((row >> 1) & 3) << 4))); \
    }                                                                              \
    short8 bf[NFR];                                                                \
    _Pragma("unroll")                                                              \
    for (int nf = 0; nf < NFR; ++nf) bf[nf] = *(const short8*)(bb + cbo[nf]);      \
    if (!(TAIL) || (KK) < KW - 3) {                                                \
        constexpr int k3_ = ((KK) + 3 < KW) ? (KK) + 3 : (KK) + 3 - KW;            \
        int boff = k3_ * KB + (((KK) + 3 < KW) ? ci : ci + 1) * 64;                \
        char* bstg = bbase + ((bcur + 3) & 3) * BBUF;                              \
        _Pragma("unroll")                                                          \
        for (int i = 0; i < B_IT; ++i)                                             \
            GLD16(bsrc[i] + boff, bstg + i * 4096 + tid * 16);                     \
    }                                                                              \
    if (!(TAIL)) {                                                                 \
        if ((KK) == 0) {                                                           \
            _Pragma("unroll")                                                      \
            for (int i = 0; i < 4; ++i)                                            \
                GLD16(asrc[i] + (size_t)(ci + 1) * 64, abn + i * 4096 + tid * 16); \
        }                                                                          \
    }                                                                              \
    __builtin_amdgcn_s_setprio(1);                                                 \
    _Pragma("unroll")                                                              \
    for (int nf = 0; nf < NFR; ++nf)                                               \
        _Pragma("unroll")                                                          \
        for (int o = 0; o < MFR; ++o)                                              \
            acc[o][nf] = __builtin_amdgcn_mfma_f32_16x16x32_bf16(afr[o], bf[nf], acc[o][nf], 0, 0, 0); \
    __builtin_amdgcn_s_setprio(0);                                                 \
    vmwait<WN>();                                                                  \
    asm volatile("" ::: "memory");                                                 \
    __builtin_amdgcn_s_barrier();                                                  \
    bcur = (bcur + 1) & 3;                                                         \
} while (0)

    for (int ci = 0; ci < CCH - 1; ++ci) {
        const char* ab = (ci & 1) ? abuf1 : abuf0;
        char* abn = (ci & 1) ? abuf0 : abuf1;
        const char* awave = ab + wid * 4096;
        if constexpr (KW == 5) {
            STEP(0, 8, false); STEP(1, 8, false); STEP(2, 4, false); STEP(3, 4, false); STEP(4, 4, false);
        } else {
            STEP(0, 6, false); STEP(1, 6, false); STEP(2, 2, false);
        }
    }
    {
        const int ci = CCH - 1;
        const char* ab = (ci & 1) ? abuf1 : abuf0;
        char* abn = (ci & 1) ? abuf0 : abuf1; (void)abn;
        const char* awave = ab + wid * 4096;
        if constexpr (KW == 5) {
            STEP(0, 4, true); STEP(1, 4, true); STEP(2, 2, true); STEP(3, 0, true); STEP(4, 0, true);
        } else {
            STEP(0, 1, true); STEP(1, 0, true); STEP(2, 0, true);
        }
    }
#undef STEP

    const int bt = m * 4 + wid;
    #pragma unroll
    for (int nf = 0; nf < NFR; ++nf) {
        float mx = -INFINITY;
        #pragma unroll
        for (int o = 0; o < MFR; ++o) {
            int rb = o * 16 + lq * 4;
            #pragma unroll
            for (int j = 0; j < 4; ++j)
                if (rb + j < LOUT) mx = fmaxf(mx, acc[o][nf][j]);
        }
        mx = fmaxf(mx, __shfl_xor(mx, 16, 64));
        mx = fmaxf(mx, __shfl_xor(mx, 32, 64));
        if (lane < 16) {
            int col = n * BN + nf * 16 + lane;
            pooled[(size_t)bt * COUT + col] = mx + bias[col];
        }
    }
}

// conv_a body (r11): pair barriers, 5-slot B ring, late A staging (k5..k8)
__device__ __forceinline__
void conv_body_a(char* smem, int m, int n,
                 const unsigned short* __restrict__ xb, const unsigned short* __restrict__ wt,
                 const float* __restrict__ bias, float* __restrict__ pooled)
{
    constexpr int LOUT = LOUTA, WIN = WA_, CINP = EAP, BN = 128, COUT = CA;
    constexpr int CCH  = CINP / 32;        // 31
    constexpr int KB   = CINP * 2;         // 1984
    constexpr int KTOTB = CINP * 10 * 2;
    constexpr int ABUF = 4 * 64 * 64;      // 16 KB
    constexpr int BBUF = BN * 64;          // 8 KB

    const int tid  = threadIdx.x;
    const int lane = tid & 63;
    const int wid  = tid >> 6;
    const int lr   = lane & 15;
    const int lq   = lane >> 4;
    const int lq16 = lq * 16;

    f32x4 acc[3][8];
    #pragma unroll
    for (int i = 0; i < 3; ++i)
        #pragma unroll
        for (int j = 0; j < 8; ++j) acc[i][j] = (f32x4){0.f, 0.f, 0.f, 0.f};

    const int aw_r = tid >> 2;
    const int aw   = (aw_r < WIN) ? aw_r : (WIN - 1);
    const int slot = tid & 3;
    const char* asrc[4];
    #pragma unroll
    for (int i = 0; i < 4; ++i)
        asrc[i] = (const char*)xb + ((size_t)((m * 4 + i) * WIN + aw)) * KB
                + ((slot * 16) ^ (((aw_r >> 1) & 3) << 4));
    const char* bsrc[2];
    #pragma unroll
    for (int i = 0; i < 2; ++i) {
        int col = (tid + i * 256) >> 2;
        bsrc[i] = (const char*)wt + (size_t)(n * BN + col) * KTOTB
                + ((slot * 16) ^ (((col >> 1) & 3) << 4));
    }

    char* const abuf0 = smem;
    char* const abuf1 = smem + ABUF;
    char* const bbase = smem + 2 * ABUF;

    int cbo[8];
    #pragma unroll
    for (int nf = 0; nf < 8; ++nf) {
        int cb = nf * 16 + lr;
        cbo[nf] = cb * 64 + (lq16 ^ (((cb >> 1) & 3) << 4));
    }

    #pragma unroll
    for (int i = 0; i < 4; ++i)
        GLD16(asrc[i], abuf0 + i * 4096 + tid * 16);
    #pragma unroll
    for (int s = 0; s < 3; ++s) {
        GLD16(bsrc[0] + s * KB, bbase + s * BBUF + tid * 16);
        GLD16(bsrc[1] + s * KB, bbase + s * BBUF + 4096 + tid * 16);
    }
    vmwait<0>();
    __builtin_amdgcn_s_barrier();

    int bcur = 0;

#define VSTEP(KK, DOA, DOBAR, WN, DOBSTG, CHN) do {                                \
    const char* bb = bbase + bcur * BBUF;                                          \
    short8 afr[3];                                                                 \
    _Pragma("unroll")                                                              \
    for (int o = 0; o < 3; ++o) {                                                  \
        int row = o * 16 + lr + (KK);                                              \
        afr[o] = *(const short8*)(awave + row * 64 + (lq16 ^ (((row >> 1) & 3) << 4))); \
    }                                                                              \
    short8 bf[8];                                                                  \
    _Pragma("unroll")                                                              \
    for (int nf = 0; nf < 8; ++nf) bf[nf] = *(const short8*)(bb + cbo[nf]);        \
    if (DOBSTG) {                                                                  \
        constexpr int K3 = ((KK) + 3 < 10) ? (KK) + 3 : (KK) - 7;                  \
        int boff = K3 * KB + (CHN) * 64;                                           \
        int b3 = bcur + 3; if (b3 >= 5) b3 -= 5;                                   \
        char* bstg = bbase + b3 * BBUF;                                            \
        GLD16(bsrc[0] + boff, bstg + tid * 16);                                    \
        GLD16(bsrc[1] + boff, bstg + 4096 + tid * 16);                             \
    }                                                                              \
    if (DOA) GLD16(asrc[(KK) - 5] + (size_t)(ci + 1) * 64,                         \
                   abn + ((KK) - 5) * 4096 + tid * 16);                            \
    __builtin_amdgcn_s_setprio(1);                                                 \
    _Pragma("unroll")                                                              \
    for (int nf = 0; nf < 8; ++nf)                                                 \
        _Pragma("unroll")                                                          \
        for (int o = 0; o < 3; ++o)                                                \
            acc[o][nf] = __builtin_amdgcn_mfma_f32_16x16x32_bf16(afr[o], bf[nf], acc[o][nf], 0, 0, 0); \
    __builtin_amdgcn_s_setprio(0);                                                 \
    if (DOBAR) { vmwait<WN>(); asm volatile("" ::: "memory");                      \
                 __builtin_amdgcn_s_barrier(); }                                   \
    bcur = (bcur == 4) ? 0 : bcur + 1;                                             \
} while (0)

    for (int ci = 0; ci < CCH - 1; ++ci) {
        const char* ab = (ci & 1) ? abuf1 : abuf0;
        char* abn = (ci & 1) ? abuf0 : abuf1;
        const char* awave = ab + wid * 4096;
        VSTEP(0, false, false, 0, true, ci);
        VSTEP(1, false, true,  2, true, ci);
        VSTEP(2, false, false, 0, true, ci);
        VSTEP(3, false, true,  2, true, ci);
        VSTEP(4, false, false, 0, true, ci);
        VSTEP(5, true,  true,  3, true, ci);
        VSTEP(6, true,  false, 0, true, ci);
        VSTEP(7, true,  true,  3, true, ci + 1);
        VSTEP(8, true,  false, 0, true, ci + 1);
        VSTEP(9, false, true,  2, true, ci + 1);
    }
    {
        const int ci = CCH - 1;
        const char* ab = (ci & 1) ? abuf1 : abuf0;
        char* abn = (ci & 1) ? abuf0 : abuf1; (void)abn;
        const char* awave = ab + wid * 4096;
        VSTEP(0, false, false, 0, true,  ci);
        VSTEP(1, false, true,  2, true,  ci);
        VSTEP(2, false, false, 0, true,  ci);
        VSTEP(3, false, true,  2, true,  ci);
        VSTEP(4, false, false, 0, true,  ci);
        VSTEP(5, false, true,  2, true,  ci);
        VSTEP(6, false, false, 0, true,  ci);
        VSTEP(7, false, true,  0, false, ci);
        VSTEP(8, false, false, 0, false, ci);
        VSTEP(9, false, true,  0, false, ci);
    }
#undef VSTEP

    const int bt = m * 4 + wid;
    #pragma unroll
    for (int nf = 0; nf < 8; ++nf) {
        float mx = -INFINITY;
        #pragma unroll
        for (int o = 0; o < 3; ++o) {
            int rb = o * 16 + lq * 4;
            #pragma unroll
            for (int j = 0; j < 4; ++j)
                if (rb + j < LOUT) mx = fmaxf(mx, acc[o][nf][j]);
        }
        mx = fmaxf(mx, __shfl_xor(mx, 16, 64));
        mx = fmaxf(mx, __shfl_xor(mx, 32, 64));
        if (lane < 16) {
            int col = n * BN + nf * 16 + lane;
            pooled[(size_t)bt * COUT + col] = mx + bias[col];
        }
    }
}

// ================= mega conv launch: A [0,768) + L [768,1152) + E [1152,1536) =================
#define CONVA_BLOCKS 768
#define CONVL_BLOCKS 384
__global__ __launch_bounds__(256, 2)
void conv_all(const unsigned short* __restrict__ xaco_p, const unsigned short* __restrict__ wtA,
              const float* __restrict__ convA_b, float* __restrict__ pA,
              const unsigned short* __restrict__ xlin_p, const unsigned short* __restrict__ wtL,
              const float* __restrict__ convL_b, float* __restrict__ pL,
              const unsigned short* __restrict__ hbuf, const unsigned short* __restrict__ wtE,
              const float* __restrict__ convE_b, float* __restrict__ pE)
{
    __shared__ __align__(16) char smem[73728];
    int bx = blockIdx.x;
    if (bx < CONVA_BLOCKS) {
        int xcd = bx & 7;
        int n = xcd & 1;
        int m = (xcd >> 1) * 96 + (bx >> 3);
        conv_body_a(smem, m, n, xaco_p, wtA, convA_b, pA);
    } else if (bx < CONVA_BLOCKS + CONVL_BLOCKS) {
        conv_body_v10<LOUTL, WL_, ELP, 5, 128, 2, CL>(smem, bx - CONVA_BLOCKS, 0,
                                                      xlin_p, wtL, convL_b, pL);
    } else {
        conv_body_v10<LOUTE, WE_, HH, 3, 64, 2, CE>(smem, bx - CONVA_BLOCKS - CONVL_BLOCKS, 0,
                                                    hbuf, wtE, convE_b, pE);
    }
}

// ---------------- fused highway v2: sample-batched (A:8/blk, L:16/blk, E:32/blk) ----------------
#define HWA_BLOCKS 192
#define HWL_BLOCKS 96
#define HWE_BLOCKS 48
__global__ __launch_bounds__(256)
void highway_v2(const float* __restrict__ pL, const float* __restrict__ pA, const float* __restrict__ pE,
                const float* __restrict__ WpTL, const float* __restrict__ bpL,
                const float* __restrict__ WgTL, const float* __restrict__ bgL,
                const float* __restrict__ WpTA, const float* __restrict__ bpA,
                const float* __restrict__ WgTA, const float* __restrict__ bgA,
                const float* __restrict__ WpTE, const float* __restrict__ bpE,
                const float* __restrict__ WgTE, const float* __restrict__ bgE,
                float* __restrict__ out) {
    __shared__ float xs[2048];
    int bx = blockIdx.x;
    int tid = threadIdx.x;
    if (bx < HWA_BLOCKS) {                      // acoustic: 8 samples x 256 cols
        int bt0 = bx * 8;
        #pragma unroll
        for (int s = 0; s < 8; ++s) xs[s * 256 + tid] = pA[(size_t)(bt0 + s) * 256 + tid];
        __syncthreads();
        float p[8], g[8];
        #pragma unroll
        for (int s = 0; s < 8; ++s) { p[s] = bpA[tid]; g[s] = bgA[tid]; }
        for (int c = 0; c < 256; ++c) {
            float wp = WpTA[c * 256 + tid], wg = WgTA[c * 256 + tid];
            #pragma unroll
            for (int s = 0; s < 8; ++s) {
                float xv = xs[s * 256 + c];
                p[s] += xv * wp; g[s] += xv * wg;
            }
        }
        #pragma unroll
        for (int s = 0; s < 8; ++s) {
            float pp = fmaxf(p[s], 0.f);
            float gg = sigmf(g[s]);
            out[(size_t)(bt0 + s) * 448 + 128 + tid] = gg * pp + (1.f - gg) * xs[s * 256 + tid];
        }
    } else if (bx < HWA_BLOCKS + HWL_BLOCKS) {  // linguistic: 16 samples x 128 cols
        int bt0 = (bx - HWA_BLOCKS) * 16;
        for (int i = tid; i < 16 * 128; i += 256) xs[i] = pL[(size_t)bt0 * 128 + i];
        __syncthreads();
        int j = tid & 127, h = tid >> 7;
        float p[8], g[8];
        #pragma unroll
        for (int s = 0; s < 8; ++s) { p[s] = bpL[j]; g[s] = bgL[j]; }
        for (int c = 0; c < 128; ++c) {
            float wp = WpTL[c * 128 + j], wg = WgTL[c * 128 + j];
            #pragma unroll
            for (int s = 0; s < 8; ++s) {
                float xv = xs[(h * 8 + s) * 128 + c];
                p[s] += xv * wp; g[s] += xv * wg;
            }
        }
        #pragma unroll
        for (int s = 0; s < 8; ++s) {
            float pp = fmaxf(p[s], 0.f);
            float gg = sigmf(g[s]);
            out[(size_t)(bt0 + h * 8 + s) * 448 + j] = gg * pp + (1.f - gg) * xs[(h * 8 + s) * 128 + j];
        }
    } else {                                    // emotient: 32 samples x 64 cols
        int bt0 = (bx - HWA_BLOCKS - HWL_BLOCKS) * 32;
        for (int i = tid; i < 32 * 64; i += 256) xs[i] = pE[(size_t)bt0 * 64 + i];
        __syncthreads();
        int j = tid & 63, grp = tid >> 6;
        float p[8], g[8];
        #pragma unroll
        for (int s = 0; s < 8; ++s) { p[s] = bpE[j]; g[s] = bgE[j]; }
        for (int c = 0; c < 64; ++c) {
            float wp = WpTE[c * 64 + j], wg = WgTE[c * 64 + j];
            #pragma unroll
            for (int s = 0; s < 8; ++s) {
                float xv = xs[(grp * 8 + s) * 64 + c];
                p[s] += xv * wp; g[s] += xv * wg;
            }
        }
        #pragma unroll
        for (int s = 0; s < 8; ++s) {
            float pp = fmaxf(p[s], 0.f);
            float gg = sigmf(g[s]);
            out[(size_t)(bt0 + grp * 8 + s) * 448 + 384 + j] = gg * pp + (1.f - gg) * xs[(grp * 8 + s) * 64 + j];
        }
    }
}

// ================= fallback path (tiny workspace): slow but correct =================
__global__ void prep_fallback(const float* hwL_Wp, float* WpTL, const float* hwL_Wg, float* WgTL,
                              const float* hwA_Wp, float* WpTA, const float* hwA_Wg, float* WgTA,
                              const float* hwE_Wp, float* WpTE, const float* hwE_Wg, float* WgTE,
                              const float* lstm_Wih, float* WihT, const float* lstm_Whh, float* WhhT) {
    constexpr int S1 = 16384, S2 = 16384, S3 = 65536, S4 = 65536, S5 = 4096, S6 = 4096;
    constexpr int S7 = 512 * 20, S8 = 512 * 128;
    constexpr int TOTAL = S1 + S2 + S3 + S4 + S5 + S6 + S7 + S8;
    int stride = gridDim.x * blockDim.x;
    for (int i = blockIdx.x * blockDim.x + threadIdx.x; i < TOTAL; i += stride) {
        int idx = i;
        if (idx < S1) { tr_one(hwL_Wp, WpTL, 128, 128, idx); continue; } idx -= S1;
        if (idx < S2) { tr_one(hwL_Wg, WgTL, 128, 128, idx); continue; } idx -= S2;
        if (idx < S3) { tr_one(hwA_Wp, WpTA, 256, 256, idx); continue; } idx -= S3;
        if (idx < S4) { tr_one(hwA_Wg, WgTA, 256, 256, idx); continue; } idx -= S4;
        if (idx < S5) { tr_one(hwE_Wp, WpTE, 64, 64, idx); continue; } idx -= S5;
        if (idx < S6) { tr_one(hwE_Wg, WgTE, 64, 64, idx); continue; } idx -= S6;
        if (idx < S7) { tr_one(lstm_Wih, WihT, 512, 20, idx); continue; } idx -= S7;
        tr_one(lstm_Whh, WhhT, 512, 128, idx);
    }
}

__global__ __launch_bounds__(512)
void lstm_kernel_f32(const float* __restrict__ x, const int* __restrict__ lens,
                     const float* __restrict__ WihT, const float* __restrict__ WhhT,
                     const float* __restrict__ bih, const float* __restrict__ bhh,
                     float* __restrict__ hout) {
    int bt = blockIdx.x;
    int j  = threadIdx.x;
    __shared__ float xs[WE_][EE];
    __shared__ __align__(16) float hs[HH];
    __shared__ float zs[512];
    for (int idx = j; idx < WE_ * EE; idx += 512)
        ((float*)xs)[idx] = x[(size_t)bt * WE_ * EE + idx];
    if (j < HH) hs[j] = 0.f;
    float wih[EE];
    #pragma unroll
    for (int e = 0; e < EE; ++e) wih[e] = WihT[e * 512 + j];
    float whh[HH];
    #pragma unroll
    for (int h = 0; h < HH; ++h) whh[h] = WhhT[h * 512 + j];
    float bjv = bih[j] + bhh[j];
    float c_reg = 0.f;
    int len = lens[bt];
    __syncthreads();
    for (int t = 0; t < WE_; ++t) {
        float z = bjv;
        #pragma unroll
        for (int e = 0; e < EE; ++e) z += wih[e] * xs[t][e];
        const float4* h4 = (const float4*)hs;
        #pragma unroll
        for (int q = 0; q < HH / 4; ++q) {
            float4 hv = h4[q];
            z += whh[4*q+0] * hv.x + whh[4*q+1] * hv.y
               + whh[4*q+2] * hv.z + whh[4*q+3] * hv.w;
        }
        zs[j] = z;
        __syncthreads();
        if (j < HH) {
            float zi = zs[j], zf = zs[HH + j], zg = zs[2*HH + j], zo = zs[3*HH + j];
            float si = 1.f / (1.f + expf(-zi));
            float sf = 1.f / (1.f + expf(-zf));
            float so = 1.f / (1.f + expf(-zo));
            float tg = tanhf(zg);
            float c2 = sf * c_reg + si * tg;
            float h2 = so * tanhf(c2);
            bool valid = (t < len);
            float hn = valid ? h2 : hs[j];
            c_reg    = valid ? c2 : c_reg;
            hout[((size_t)bt * WE_ + t) * HH + j] = valid ? h2 : 0.f;
            hs[j] = hn;
        }
        __syncthreads();
    }
}

template<int CIN, int WIN, int COUT, int KDIM, int LOUT>
__global__ __launch_bounds__(256)
void conv_pool_simple(const float* __restrict__ x, const float* __restrict__ w,
                      const float* __restrict__ bias, float* __restrict__ pooled)
{
    constexpr int KW = KDIM / CIN;
    int bt = blockIdx.x;
    int co = blockIdx.y * 64 + (threadIdx.x & 63);
    int seg = threadIdx.x >> 6;
    __shared__ float part[4][64];
    float m = -INFINITY;
    for (int l = seg; l < LOUT; l += 4) {
        float acc = 0.f;
        for (int k = 0; k < KW; ++k) {
            const float* xr = x + ((size_t)bt * WIN + l + k) * CIN;
            const float* wr = w + ((size_t)co * CIN) * KW + k;
            for (int cc = 0; cc < CIN; ++cc) acc += xr[cc] * wr[(size_t)cc * KW];
        }
        m = fmaxf(m, acc);
    }
    part[seg][threadIdx.x & 63] = m;
    __syncthreads();
    if (threadIdx.x < 64) {
        float mm = fmaxf(fmaxf(part[0][threadIdx.x], part[1][threadIdx.x]),
                         fmaxf(part[2][threadIdx.x], part[3][threadIdx.x]));
        pooled[(size_t)bt * COUT + co] = mm + bias[co];
    }
}

// ---------------- launch ----------------
static inline int cdiv(int a, int b) { return (a + b - 1) / b; }

extern "C" void kernel_launch(void* const* d_in, const int* in_sizes, int n_in,
                              void* d_out, int out_size, void* d_ws, size_t ws_size,
                              hipStream_t stream) {
    const float* x_lin  = (const float*)d_in[0];
    const float* x_aco  = (const float*)d_in[1];
    const float* x_emo  = (const float*)d_in[2];
    const int*   wlen   = (const int*)  d_in[3];
    const float* convL_w = (const float*)d_in[5];
    const float* convL_b = (const float*)d_in[6];
    const float* convA_w = (const float*)d_in[7];
    const float* convA_b = (const float*)d_in[8];
    const float* convE_w = (const float*)d_in[9];
    const float* convE_b = (const float*)d_in[10];
    const float* hwL_Wp = (const float*)d_in[11];
    const float* hwL_bp = (const float*)d_in[12];
    const float* hwL_Wg = (const float*)d_in[13];
    const float* hwL_bg = (const float*)d_in[14];
    const float* hwA_Wp = (const float*)d_in[15];
    const float* hwA_bp = (const float*)d_in[16];
    const float* hwA_Wg = (const float*)d_in[17];
    const float* hwA_bg = (const float*)d_in[18];
    const float* hwE_Wp = (const float*)d_in[19];
    const float* hwE_bp = (const float*)d_in[20];
    const float* hwE_Wg = (const float*)d_in[21];
    const float* hwE_bg = (const float*)d_in[22];
    const float* lstm_Wih = (const float*)d_in[23];
    const float* lstm_Whh = (const float*)d_in[24];
    const float* lstm_bih = (const float*)d_in[25];
    const float* lstm_bhh = (const float*)d_in[26];
    float* out = (float*)d_out;

    // ---- workspace carve (256B aligned) ----
    char* p0 = (char*)d_ws;
    char* p = p0;
    auto alloc = [&](size_t bytes) { char* r = p; p += (bytes + 255) & ~(size_t)255; return r; };
    float* WpTL = (float*)alloc((size_t)CL * CL * 4);
    float* WgTL = (float*)alloc((size_t)CL * CL * 4);
    float* WpTA = (float*)alloc((size_t)CA * CA * 4);
    float* WgTA = (float*)alloc((size_t)CA * CA * 4);
    float* WpTE = (float*)alloc((size_t)CE * CE * 4);
    float* WgTE = (float*)alloc((size_t)CE * CE * 4);
    float* WihT = (float*)alloc((size_t)EE * 512 * 4);
    float* WhhT = (float*)alloc((size_t)HH * 512 * 4);
    void*  hbuf = (void*)alloc((size_t)BTOT * WE_ * HH * 4);
    float* pL   = (float*)alloc((size_t)BTOT * CL * 4);
    float* pA   = (float*)alloc((size_t)BTOT * CA * 4);
    float* pE   = (float*)alloc((size_t)BTOT * CE * 4);
    unsigned short* wtA = (unsigned short*)alloc((size_t)CA * KPA * 2);
    unsigned short* wtL = (unsigned short*)alloc((size_t)CL * KPL * 2);
    unsigned short* wtE = (unsigned short*)alloc((size_t)CE * KPE * 2);
    unsigned short* xlin_p = (unsigned short*)alloc((size_t)BTOT * WL_ * ELP * 2 + 64);
    unsigned short* xaco_p = (unsigned short*)alloc((size_t)BTOT * WA_ * EAP * 2 + 64);
    size_t need = (size_t)(p - p0);
    bool big = ws_size >= need;

    if (big) {
        lstm_cvt_prep<<<LSTM_BLOCKS + AUX_BLOCKS, 512, 0, stream>>>(
            x_emo, lstm_Wih, lstm_Whh, lstm_bih, lstm_bhh, wlen, (unsigned short*)hbuf,
            x_aco, x_lin, xaco_p, xlin_p,
            hwL_Wp, WpTL, hwL_Wg, WgTL, hwA_Wp, WpTA, hwA_Wg, WgTA, hwE_Wp, WpTE, hwE_Wg, WgTE,
            convL_w, wtL, convE_w, wtE, convA_w, wtA);
        conv_all<<<1536, 256, 0, stream>>>(xaco_p, wtA, convA_b, pA,
                                           xlin_p, wtL, convL_b, pL,
                                           (const unsigned short*)hbuf, wtE, convE_b, pE);
        highway_v2<<<HWA_BLOCKS + HWL_BLOCKS + HWE_BLOCKS, 256, 0, stream>>>(
            pL, pA, pE, WpTL, hwL_bp, WgTL, hwL_bg, WpTA, hwA_bp, WgTA, hwA_bg,
            WpTE, hwE_bp, WgTE, hwE_bg, out);
    } else {
        prep_fallback<<<512, 256, 0, stream>>>(hwL_Wp, WpTL, hwL_Wg, WgTL, hwA_Wp, WpTA, hwA_Wg, WgTA,
                                               hwE_Wp, WpTE, hwE_Wg, WgTE, lstm_Wih, WihT, lstm_Whh, WhhT);
        lstm_kernel_f32<<<BTOT, 512, 0, stream>>>(x_emo, wlen, WihT, WhhT, lstm_bih, lstm_bhh, (float*)hbuf);
        conv_pool_simple<EA, WA_, CA, KDIMA, LOUTA>
            <<<dim3(BTOT, CA / 64), 256, 0, stream>>>(x_aco, convA_w, convA_b, pA);
        conv_pool_simple<EL, WL_, CL, KDIML, LOUTL>
            <<<dim3(BTOT, CL / 64), 256, 0, stream>>>(x_lin, convL_w, convL_b, pL);
        conv_pool_simple<HH, WE_, CE, KDIME, LOUTE>
            <<<dim3(BTOT, CE / 64), 256, 0, stream>>>((const float*)hbuf, convE_w, convE_b, pE);
        highway_v2<<<HWA_BLOCKS + HWL_BLOCKS + HWE_BLOCKS, 256, 0, stream>>>(
            pL, pA, pE, WpTL, hwL_bp, WgTL, hwL_bg, WpTA, hwA_bp, WgTA, hwA_bg,
            WpTE, hwE_bp, WgTE, hwE_bg, out);
    }
}

// Round 14
// 535.150 us; speedup vs baseline: 1.6254x; 1.0052x over previous
//
#include <hip/hip_runtime.h>
#include <hip/hip_bf16.h>
#include <math.h>

// ---------------- problem dims (fixed by setup_inputs) ----------------
#define BTOT 1536            // B*T = 32*48
// linguistic
#define EL 300
#define ELP 320              // padded CIN (10 c-chunks of 32)
#define WL_ 33
#define CL 128
#define LOUTL 29
#define KPL 1600
// acoustic
#define EA 988
#define EAP 992              // 31 c-chunks
#define WA_ 50
#define CA 256
#define LOUTA 41
#define KPA 9920
// emotient
#define EE 20
#define WE_ 30
#define HH 128
#define CE 64
#define LOUTE 28
#define KPE 384
// fallback K dims
#define KDIML 1500
#define KDIMA 9880
#define KDIME 384

typedef __attribute__((ext_vector_type(4))) float f32x4;
typedef __attribute__((ext_vector_type(8))) short short8;

// RNE float->bf16 (inputs finite)
__device__ __forceinline__ unsigned short f2bf(float f) {
    unsigned int x = __float_as_uint(f);
    unsigned int r = (x + 0x7fffu + ((x >> 16) & 1u)) >> 16;
    return (unsigned short)r;
}

__device__ __forceinline__ float sigmf(float x) {
    return __builtin_amdgcn_rcpf(1.f + __expf(-x));
}
__device__ __forceinline__ float tanh_fast(float x) {
    return 1.f - 2.f * __builtin_amdgcn_rcpf(1.f + __expf(2.f * x));
}

#define GLD16(gp, lp) __builtin_amdgcn_global_load_lds( \
    (const __attribute__((address_space(1))) void*)(gp), \
    (__attribute__((address_space(3))) void*)(lp), 16, 0, 0)

template<int N> __device__ __forceinline__ void vmwait() {
    if constexpr (N == 0) asm volatile("s_waitcnt vmcnt(0)" ::: "memory");
    else if constexpr (N == 1) asm volatile("s_waitcnt vmcnt(1)" ::: "memory");
    else if constexpr (N == 2) asm volatile("s_waitcnt vmcnt(2)" ::: "memory");
    else if constexpr (N == 3) asm volatile("s_waitcnt vmcnt(3)" ::: "memory");
    else if constexpr (N == 4) asm volatile("s_waitcnt vmcnt(4)" ::: "memory");
    else if constexpr (N == 6) asm volatile("s_waitcnt vmcnt(6)" ::: "memory");
    else if constexpr (N == 8) asm volatile("s_waitcnt vmcnt(8)" ::: "memory");
    else static_assert(N == 0, "add case");
}

// ---------------- small helpers ----------------
__device__ __forceinline__ void tr_one(const float* a, float* at, int R, int C, int idx) {
    int r = idx / C, c = idx - r * C;
    at[c * R + r] = a[idx];
}
template<int CIN, int CINP, int KW, int COUT, int KPAD>
__device__ __forceinline__ void wt_one(const float* w, unsigned short* wt, int idx) {
    int co = idx / KPAD;
    int p  = idx - co * KPAD;
    int k  = p / CINP;
    int c  = p - k * CINP;
    float v = 0.f;
    if (k < KW && c < CIN) v = w[(co * CIN + c) * KW + k];
    wt[idx] = f2bf(v);
}
template<int CIN, int CINP>
__device__ __forceinline__ void cvt_chunk(const float* in, unsigned short* out, int idx) {
    constexpr int CH = CINP / 8;
    int row = idx / CH, c0 = (idx - row * CH) * 8;
    const float* src = in + (size_t)row * CIN + c0;
    union { short8 s; unsigned short u[8]; } o;
    if (c0 + 8 <= CIN) {
        float4 v0 = *(const float4*)src;
        float4 v1 = *(const float4*)(src + 4);
        o.u[0]=f2bf(v0.x); o.u[1]=f2bf(v0.y); o.u[2]=f2bf(v0.z); o.u[3]=f2bf(v0.w);
        o.u[4]=f2bf(v1.x); o.u[5]=f2bf(v1.y); o.u[6]=f2bf(v1.z); o.u[7]=f2bf(v1.w);
    } else {
        #pragma unroll
        for (int j = 0; j < 8; ++j) o.u[j] = (c0 + j < CIN) ? f2bf(src[j]) : (unsigned short)0;
    }
    *(short8*)(out + (size_t)row * CINP + c0) = o.s;
}

// ================= prep_all: highway transposes + all conv weights + lstm weights (bf16) =================
template<bool BIG>
__global__ void prep_all(const float* hwL_Wp, float* WpTL, const float* hwL_Wg, float* WgTL,
                         const float* hwA_Wp, float* WpTA, const float* hwA_Wg, float* WgTA,
                         const float* hwE_Wp, float* WpTE, const float* hwE_Wg, float* WgTE,
                         const float* lstm_Wih, float* WihT, const float* lstm_Whh, float* WhhT,
                         const float* convL_w, unsigned short* wtL,
                         const float* convE_w, unsigned short* wtE,
                         const float* convA_w, unsigned short* wtA,
                         unsigned short* whh_bf, unsigned short* wihp_bf) {
    constexpr int S1 = 16384, S2 = 16384, S3 = 65536, S4 = 65536, S5 = 4096, S6 = 4096;
    constexpr int S7 = 512 * 20, S8 = 512 * 128;
    constexpr int S9 = 128 * KPL, S10 = 64 * KPE, S11 = 512 * 128, S12 = 512 * 32;
    constexpr int S13 = CA * KPA;
    constexpr int SMALL = S1 + S2 + S3 + S4 + S5 + S6 + S7 + S8;
    constexpr int TOTAL = BIG ? (SMALL + S9 + S10 + S11 + S12 + S13) : SMALL;
    int stride = gridDim.x * blockDim.x;
    for (int i = blockIdx.x * blockDim.x + threadIdx.x; i < TOTAL; i += stride) {
        int idx = i;
        if (idx < S1) { tr_one(hwL_Wp, WpTL, 128, 128, idx); continue; } idx -= S1;
        if (idx < S2) { tr_one(hwL_Wg, WgTL, 128, 128, idx); continue; } idx -= S2;
        if (idx < S3) { tr_one(hwA_Wp, WpTA, 256, 256, idx); continue; } idx -= S3;
        if (idx < S4) { tr_one(hwA_Wg, WgTA, 256, 256, idx); continue; } idx -= S4;
        if (idx < S5) { tr_one(hwE_Wp, WpTE, 64, 64, idx); continue; } idx -= S5;
        if (idx < S6) { tr_one(hwE_Wg, WgTE, 64, 64, idx); continue; } idx -= S6;
        if (idx < S7) { tr_one(lstm_Wih, WihT, 512, 20, idx); continue; } idx -= S7;
        if (idx < S8) { tr_one(lstm_Whh, WhhT, 512, 128, idx); continue; } idx -= S8;
        if constexpr (BIG) {
            if (idx < S9) { wt_one<EL, ELP, 5, CL, KPL>(convL_w, wtL, idx); continue; } idx -= S9;
            if (idx < S10) { wt_one<HH, HH, 3, CE, KPE>(convE_w, wtE, idx); continue; } idx -= S10;
            if (idx < S11) { whh_bf[idx] = f2bf(lstm_Whh[idx]); continue; } idx -= S11;
            if (idx < S12) { int col = idx >> 5, e = idx & 31;
                             wihp_bf[idx] = (e < 20) ? f2bf(lstm_Wih[col * 20 + e]) : (unsigned short)0;
                             continue; } idx -= S12;
            wt_one<EA, EAP, 10, CA, KPA>(convA_w, wtA, idx);
        }
    }
}

// ================= fused LSTM (blocks 0..95) + both fp32->bf16 converts (blocks 96+) =================
#define LSTM_BLOCKS 96
#define CVT_BLOCKS 1952

__global__ __launch_bounds__(512, 1)
void lstm_cvt(const float* __restrict__ x_emo,
              const unsigned short* __restrict__ wihp_bf, const unsigned short* __restrict__ whh_bf,
              const float* __restrict__ bih, const float* __restrict__ bhh,
              const int* __restrict__ lens, unsigned short* __restrict__ hbuf,
              const float* __restrict__ xa, const float* __restrict__ xl,
              unsigned short* __restrict__ outa, unsigned short* __restrict__ outl)
{
    __shared__ __align__(16) unsigned short xq[WE_ * 16 * 32];  // 30 KB
    __shared__ __align__(16) char h_s[2 * 16 * HH * 2];         // 8 KB dbuf, swizzled

    if (blockIdx.x >= LSTM_BLOCKS) {
        constexpr int NAC = (BTOT * WA_) * (EAP / 8);
        constexpr int NLC = (BTOT * WL_) * (ELP / 8);
        int stride = CVT_BLOCKS * 512;
        for (int i = (blockIdx.x - LSTM_BLOCKS) * 512 + threadIdx.x; i < NAC + NLC; i += stride) {
            if (i < NAC) cvt_chunk<EA, EAP>(xa, outa, i);
            else         cvt_chunk<EL, ELP>(xl, outl, i - NAC);
        }
        return;
    }

    // ---- LSTM path: 16 samples/block ----
    const int tid  = threadIdx.x;
    const int w    = tid >> 6;
    const int lane = tid & 63;
    const int lr   = lane & 15;
    const int lq   = lane >> 4;
    const int s0   = blockIdx.x * 16;
    const int c    = w * 16 + lr;     // gate-col within 128

    short8 bfr[4][4];
    short8 bw[4];
    float bj[4];
    #pragma unroll
    for (int g = 0; g < 4; ++g) {
        int col = g * 128 + c;
        #pragma unroll
        for (int kt = 0; kt < 4; ++kt)
            bfr[g][kt] = *(const short8*)(whh_bf + (size_t)col * 128 + kt * 32 + lq * 8);
        bw[g] = *(const short8*)(wihp_bf + (size_t)col * 32 + lq * 8);
        bj[g] = bih[col] + bhh[col];
    }
    int len4[4];
    #pragma unroll
    for (int j = 0; j < 4; ++j) len4[j] = lens[s0 + lq * 4 + j];

    for (int i = tid; i < WE_ * 16 * 32; i += 512) {
        int t = i >> 9, r = (i >> 5) & 15, e = i & 31;
        xq[i] = (e < 20) ? f2bf(x_emo[(((size_t)(s0 + r) * WE_) + t) * 20 + e]) : (unsigned short)0;
    }
    for (int i = tid; i < 2048; i += 512) ((unsigned int*)h_s)[i] = 0u;

    float c_prev[4] = {0.f, 0.f, 0.f, 0.f};
    unsigned short hb_prev[4] = {0, 0, 0, 0};
    __syncthreads();

    for (int t = 0; t < WE_; ++t) {
        const char* hsr = h_s + (t & 1) * 4096;
        char* hsw = h_s + ((t & 1) ^ 1) * 4096;
        short8 ax = *(const short8*)((const char*)xq + (size_t)(t * 16 + lr) * 64 + lq * 16);
        short8 af[4];
        #pragma unroll
        for (int kt = 0; kt < 4; ++kt)
            af[kt] = *(const short8*)(hsr + ((lr * 256 + kt * 64 + lq * 16) ^ ((lr & 7) << 4)));
        f32x4 acc[4];
        #pragma unroll
        for (int g = 0; g < 4; ++g)
            acc[g] = __builtin_amdgcn_mfma_f32_16x16x32_bf16(ax, bw[g], (f32x4){0.f,0.f,0.f,0.f}, 0, 0, 0);
        #pragma unroll
        for (int kt = 0; kt < 4; ++kt)
            #pragma unroll
            for (int g = 0; g < 4; ++g)
                acc[g] = __builtin_amdgcn_mfma_f32_16x16x32_bf16(af[kt], bfr[g][kt], acc[g], 0, 0, 0);
        #pragma unroll
        for (int j = 0; j < 4; ++j) {
            int s = lq * 4 + j;
            float zi = acc[0][j] + bj[0];
            float zf = acc[1][j] + bj[1];
            float zg = acc[2][j] + bj[2];
            float zo = acc[3][j] + bj[3];
            float si = sigmf(zi), sf = sigmf(zf), so = sigmf(zo);
            float tg = tanh_fast(zg);
            float c2 = sf * c_prev[j] + si * tg;
            float h2 = so * tanh_fast(c2);
            bool valid = (t < len4[j]);
            c_prev[j] = valid ? c2 : c_prev[j];
            unsigned short h2b = f2bf(h2);
            unsigned short hn = valid ? h2b : hb_prev[j];
            hb_prev[j] = hn;
            *(unsigned short*)(hsw + (((s * HH + c) * 2) ^ ((s & 7) << 4))) = hn;
            hbuf[(((size_t)(s0 + s) * WE_) + t) * HH + c] = valid ? h2b : (unsigned short)0;
        }
        __syncthreads();
    }
}

// ================= conv bodies (device functions; proven r10/r11 schedules) =================
template<int LOUT, int WIN, int CINP, int KW, int BN, int MFR, int COUT>
__device__ __forceinline__
void conv_body_v10(char* smem, int m, int n,
                   const unsigned short* __restrict__ xb, const unsigned short* __restrict__ wt,
                   const float* __restrict__ bias, float* __restrict__ pooled)
{
    constexpr int CCH   = CINP / 32;
    constexpr int KB    = CINP * 2;
    constexpr int KTOTB = CINP * KW * 2;
    constexpr int NFR   = BN / 16;
    constexpr int B_IT  = BN / 64;
    constexpr int ABUF  = 4 * 64 * 64;
    constexpr int BBUF  = BN * 64;

    const int tid  = threadIdx.x;
    const int lane = tid & 63;
    const int wid  = tid >> 6;
    const int lr   = lane & 15;
    const int lq   = lane >> 4;
    const int lq16 = lq * 16;

    f32x4 acc[MFR][NFR];
    #pragma unroll
    for (int i = 0; i < MFR; ++i)
        #pragma unroll
        for (int j = 0; j < NFR; ++j) acc[i][j] = (f32x4){0.f, 0.f, 0.f, 0.f};

    const int aw_r = tid >> 2;
    const int aw   = (aw_r < WIN) ? aw_r : (WIN - 1);
    const int slot = tid & 3;
    const char* asrc[4];
    #pragma unroll
    for (int i = 0; i < 4; ++i)
        asrc[i] = (const char*)xb + ((size_t)((m * 4 + i) * WIN + aw)) * KB
                + ((slot * 16) ^ (((aw_r >> 1) & 3) << 4));
    const char* bsrc[B_IT];
    #pragma unroll
    for (int i = 0; i < B_IT; ++i) {
        int col = (tid + i * 256) >> 2;
        bsrc[i] = (const char*)wt + (size_t)(n * BN + col) * KTOTB
                + ((slot * 16) ^ (((col >> 1) & 3) << 4));
    }

    char* const abuf0 = smem;
    char* const abuf1 = smem + ABUF;
    char* const bbase = smem + 2 * ABUF;

    int cbo[NFR];
    #pragma unroll
    for (int nf = 0; nf < NFR; ++nf) {
        int cb = nf * 16 + lr;
        cbo[nf] = cb * 64 + (lq16 ^ (((cb >> 1) & 3) << 4));
    }

    #pragma unroll
    for (int i = 0; i < 4; ++i)
        GLD16(asrc[i], abuf0 + i * 4096 + tid * 16);
    #pragma unroll
    for (int s = 0; s < 3; ++s)
        #pragma unroll
        for (int i = 0; i < B_IT; ++i)
            GLD16(bsrc[i] + s * KB, bbase + s * BBUF + i * 4096 + tid * 16);
    vmwait<0>();
    __builtin_amdgcn_s_barrier();

    int bcur = 0;

#define STEP(KK, WN, TAIL) do {                                                    \
    const char* bb = bbase + bcur * BBUF;                                          \
    short8 afr[MFR];                                                               \
    _Pragma("unroll")                                                              \
    for (int o = 0; o < MFR; ++o) {                                                \
        int row = o * 16 + lr + (KK);                                              \
        afr[o] = *(const short8*)(awave + row * 64 + (lq16 ^ (((row >> 1) & 3) << 4))); \
    }                                                                              \
    short8 bf[NFR];                                                                \
    _Pragma("unroll")                                                              \
    for (int nf = 0; nf < NFR; ++nf) bf[nf] = *(const short8*)(bb + cbo[nf]);      \
    if (!(TAIL) || (KK) < KW - 3) {                                                \
        constexpr int k3_ = ((KK) + 3 < KW) ? (KK) + 3 : (KK) + 3 - KW;            \
        int boff = k3_ * KB + (((KK) + 3 < KW) ? ci : ci + 1) * 64;                \
        char* bstg = bbase + ((bcur + 3) & 3) * BBUF;                              \
        _Pragma("unroll")                                                          \
        for (int i = 0; i < B_IT; ++i)                                             \
            GLD16(bsrc[i] + boff, bstg + i * 4096 + tid * 16);                     \
    }                                                                              \
    if (!(TAIL)) {                                                                 \
        if ((KK) == 0) {                                                           \
            _Pragma("unroll")                                                      \
            for (int i = 0; i < 4; ++i)                                            \
                GLD16(asrc[i] + (size_t)(ci + 1) * 64, abn + i * 4096 + tid * 16); \
        }                                                                          \
    }                                                                              \
    __builtin_amdgcn_s_setprio(1);                                                 \
    _Pragma("unroll")                                                              \
    for (int nf = 0; nf < NFR; ++nf)                                               \
        _Pragma("unroll")                                                          \
        for (int o = 0; o < MFR; ++o)                                              \
            acc[o][nf] = __builtin_amdgcn_mfma_f32_16x16x32_bf16(afr[o], bf[nf], acc[o][nf], 0, 0, 0); \
    __builtin_amdgcn_s_setprio(0);                                                 \
    vmwait<WN>();                                                                  \
    asm volatile("" ::: "memory");                                                 \
    __builtin_amdgcn_s_barrier();                                                  \
    bcur = (bcur + 1) & 3;                                                         \
} while (0)

    for (int ci = 0; ci < CCH - 1; ++ci) {
        const char* ab = (ci & 1) ? abuf1 : abuf0;
        char* abn = (ci & 1) ? abuf0 : abuf1;
        const char* awave = ab + wid * 4096;
        if constexpr (KW == 5) {
            STEP(0, 8, false); STEP(1, 8, false); STEP(2, 4, false); STEP(3, 4, false); STEP(4, 4, false);
        } else {
            STEP(0, 6, false); STEP(1, 6, false); STEP(2, 2, false);
        }
    }
    {
        const int ci = CCH - 1;
        const char* ab = (ci & 1) ? abuf1 : abuf0;
        char* abn = (ci & 1) ? abuf0 : abuf1; (void)abn;
        const char* awave = ab + wid * 4096;
        if constexpr (KW == 5) {
            STEP(0, 4, true); STEP(1, 4, true); STEP(2, 2, true); STEP(3, 0, true); STEP(4, 0, true);
        } else {
            STEP(0, 1, true); STEP(1, 0, true); STEP(2, 0, true);
        }
    }
#undef STEP

    const int bt = m * 4 + wid;
    #pragma unroll
    for (int nf = 0; nf < NFR; ++nf) {
        float mx = -INFINITY;
        #pragma unroll
        for (int o = 0; o < MFR; ++o) {
            int rb = o * 16 + lq * 4;
            #pragma unroll
            for (int j = 0; j < 4; ++j)
                if (rb + j < LOUT) mx = fmaxf(mx, acc[o][nf][j]);
        }
        mx = fmaxf(mx, __shfl_xor(mx, 16, 64));
        mx = fmaxf(mx, __shfl_xor(mx, 32, 64));
        if (lane < 16) {
            int col = n * BN + nf * 16 + lane;
            pooled[(size_t)bt * COUT + col] = mx + bias[col];
        }
    }
}

// conv_a body (r11): pair barriers, 5-slot B ring, late A staging (k5..k8)
__device__ __forceinline__
void conv_body_a(char* smem, int m, int n,
                 const unsigned short* __restrict__ xb, const unsigned short* __restrict__ wt,
                 const float* __restrict__ bias, float* __restrict__ pooled)
{
    constexpr int LOUT = LOUTA, WIN = WA_, CINP = EAP, BN = 128, COUT = CA;
    constexpr int CCH  = CINP / 32;        // 31
    constexpr int KB   = CINP * 2;         // 1984
    constexpr int KTOTB = CINP * 10 * 2;
    constexpr int ABUF = 4 * 64 * 64;      // 16 KB
    constexpr int BBUF = BN * 64;          // 8 KB

    const int tid  = threadIdx.x;
    const int lane = tid & 63;
    const int wid  = tid >> 6;
    const int lr   = lane & 15;
    const int lq   = lane >> 4;
    const int lq16 = lq * 16;

    f32x4 acc[3][8];
    #pragma unroll
    for (int i = 0; i < 3; ++i)
        #pragma unroll
        for (int j = 0; j < 8; ++j) acc[i][j] = (f32x4){0.f, 0.f, 0.f, 0.f};

    const int aw_r = tid >> 2;
    const int aw   = (aw_r < WIN) ? aw_r : (WIN - 1);
    const int slot = tid & 3;
    const char* asrc[4];
    #pragma unroll
    for (int i = 0; i < 4; ++i)
        asrc[i] = (const char*)xb + ((size_t)((m * 4 + i) * WIN + aw)) * KB
                + ((slot * 16) ^ (((aw_r >> 1) & 3) << 4));
    const char* bsrc[2];
    #pragma unroll
    for (int i = 0; i < 2; ++i) {
        int col = (tid + i * 256) >> 2;
        bsrc[i] = (const char*)wt + (size_t)(n * BN + col) * KTOTB
                + ((slot * 16) ^ (((col >> 1) & 3) << 4));
    }

    char* const abuf0 = smem;
    char* const abuf1 = smem + ABUF;
    char* const bbase = smem + 2 * ABUF;

    int cbo[8];
    #pragma unroll
    for (int nf = 0; nf < 8; ++nf) {
        int cb = nf * 16 + lr;
        cbo[nf] = cb * 64 + (lq16 ^ (((cb >> 1) & 3) << 4));
    }

    #pragma unroll
    for (int i = 0; i < 4; ++i)
        GLD16(asrc[i], abuf0 + i * 4096 + tid * 16);
    #pragma unroll
    for (int s = 0; s < 3; ++s) {
        GLD16(bsrc[0] + s * KB, bbase + s * BBUF + tid * 16);
        GLD16(bsrc[1] + s * KB, bbase + s * BBUF + 4096 + tid * 16);
    }
    vmwait<0>();
    __builtin_amdgcn_s_barrier();

    int bcur = 0;

#define VSTEP(KK, DOA, DOBAR, WN, DOBSTG, CHN) do {                                \
    const char* bb = bbase + bcur * BBUF;                                          \
    short8 afr[3];                                                                 \
    _Pragma("unroll")                                                              \
    for (int o = 0; o < 3; ++o) {                                                  \
        int row = o * 16 + lr + (KK);                                              \
        afr[o] = *(const short8*)(awave + row * 64 + (lq16 ^ (((row >> 1) & 3) << 4))); \
    }                                                                              \
    short8 bf[8];                                                                  \
    _Pragma("unroll")                                                              \
    for (int nf = 0; nf < 8; ++nf) bf[nf] = *(const short8*)(bb + cbo[nf]);        \
    if (DOBSTG) {                                                                  \
        constexpr int K3 = ((KK) + 3 < 10) ? (KK) + 3 : (KK) - 7;                  \
        int boff = K3 * KB + (CHN) * 64;                                           \
        int b3 = bcur + 3; if (b3 >= 5) b3 -= 5;                                   \
        char* bstg = bbase + b3 * BBUF;                                            \
        GLD16(bsrc[0] + boff, bstg + tid * 16);                                    \
        GLD16(bsrc[1] + boff, bstg + 4096 + tid * 16);                             \
    }                                                                              \
    if (DOA) GLD16(asrc[(KK) - 5] + (size_t)(ci + 1) * 64,                         \
                   abn + ((KK) - 5) * 4096 + tid * 16);                            \
    __builtin_amdgcn_s_setprio(1);                                                 \
    _Pragma("unroll")                                                              \
    for (int nf = 0; nf < 8; ++nf)                                                 \
        _Pragma("unroll")                                                          \
        for (int o = 0; o < 3; ++o)                                                \
            acc[o][nf] = __builtin_amdgcn_mfma_f32_16x16x32_bf16(afr[o], bf[nf], acc[o][nf], 0, 0, 0); \
    __builtin_amdgcn_s_setprio(0);                                                 \
    if (DOBAR) { vmwait<WN>(); asm volatile("" ::: "memory");                      \
                 __builtin_amdgcn_s_barrier(); }                                   \
    bcur = (bcur == 4) ? 0 : bcur + 1;                                             \
} while (0)

    for (int ci = 0; ci < CCH - 1; ++ci) {
        const char* ab = (ci & 1) ? abuf1 : abuf0;
        char* abn = (ci & 1) ? abuf0 : abuf1;
        const char* awave = ab + wid * 4096;
        VSTEP(0, false, false, 0, true, ci);
        VSTEP(1, false, true,  2, true, ci);
        VSTEP(2, false, false, 0, true, ci);
        VSTEP(3, false, true,  2, true, ci);
        VSTEP(4, false, false, 0, true, ci);
        VSTEP(5, true,  true,  3, true, ci);
        VSTEP(6, true,  false, 0, true, ci);
        VSTEP(7, true,  true,  3, true, ci + 1);
        VSTEP(8, true,  false, 0, true, ci + 1);
        VSTEP(9, false, true,  2, true, ci + 1);
    }
    {
        const int ci = CCH - 1;
        const char* ab = (ci & 1) ? abuf1 : abuf0;
        char* abn = (ci & 1) ? abuf0 : abuf1; (void)abn;
        const char* awave = ab + wid * 4096;
        VSTEP(0, false, false, 0, true,  ci);
        VSTEP(1, false, true,  2, true,  ci);
        VSTEP(2, false, false, 0, true,  ci);
        VSTEP(3, false, true,  2, true,  ci);
        VSTEP(4, false, false, 0, true,  ci);
        VSTEP(5, false, true,  2, true,  ci);
        VSTEP(6, false, false, 0, true,  ci);
        VSTEP(7, false, true,  0, false, ci);
        VSTEP(8, false, false, 0, false, ci);
        VSTEP(9, false, true,  0, false, ci);
    }
#undef VSTEP

    const int bt = m * 4 + wid;
    #pragma unroll
    for (int nf = 0; nf < 8; ++nf) {
        float mx = -INFINITY;
        #pragma unroll
        for (int o = 0; o < 3; ++o) {
            int rb = o * 16 + lq * 4;
            #pragma unroll
            for (int j = 0; j < 4; ++j)
                if (rb + j < LOUT) mx = fmaxf(mx, acc[o][nf][j]);
        }
        mx = fmaxf(mx, __shfl_xor(mx, 16, 64));
        mx = fmaxf(mx, __shfl_xor(mx, 32, 64));
        if (lane < 16) {
            int col = n * BN + nf * 16 + lane;
            pooled[(size_t)bt * COUT + col] = mx + bias[col];
        }
    }
}

// ================= mega conv launch: A [0,768) + L [768,1152) + E [1152,1536) =================
#define CONVA_BLOCKS 768
#define CONVL_BLOCKS 384
__global__ __launch_bounds__(256, 2)
void conv_all(const unsigned short* __restrict__ xaco_p, const unsigned short* __restrict__ wtA,
              const float* __restrict__ convA_b, float* __restrict__ pA,
              const unsigned short* __restrict__ xlin_p, const unsigned short* __restrict__ wtL,
              const float* __restrict__ convL_b, float* __restrict__ pL,
              const unsigned short* __restrict__ hbuf, const unsigned short* __restrict__ wtE,
              const float* __restrict__ convE_b, float* __restrict__ pE)
{
    __shared__ __align__(16) char smem[73728];
    int bx = blockIdx.x;
    if (bx < CONVA_BLOCKS) {
        int xcd = bx & 7;
        int n = xcd & 1;
        int m = (xcd >> 1) * 96 + (bx >> 3);
        conv_body_a(smem, m, n, xaco_p, wtA, convA_b, pA);
    } else if (bx < CONVA_BLOCKS + CONVL_BLOCKS) {
        conv_body_v10<LOUTL, WL_, ELP, 5, 128, 2, CL>(smem, bx - CONVA_BLOCKS, 0,
                                                      xlin_p, wtL, convL_b, pL);
    } else {
        conv_body_v10<LOUTE, WE_, HH, 3, 64, 2, CE>(smem, bx - CONVA_BLOCKS - CONVL_BLOCKS, 0,
                                                    hbuf, wtE, convE_b, pE);
    }
}

// ---------------- fused highway v2: sample-batched (A:8/blk, L:16/blk, E:32/blk) ----------------
#define HWA_BLOCKS 192
#define HWL_BLOCKS 96
#define HWE_BLOCKS 48
__global__ __launch_bounds__(256)
void highway_v2(const float* __restrict__ pL, const float* __restrict__ pA, const float* __restrict__ pE,
                const float* __restrict__ WpTL, const float* __restrict__ bpL,
                const float* __restrict__ WgTL, const float* __restrict__ bgL,
                const float* __restrict__ WpTA, const float* __restrict__ bpA,
                const float* __restrict__ WgTA, const float* __restrict__ bgA,
                const float* __restrict__ WpTE, const float* __restrict__ bpE,
                const float* __restrict__ WgTE, const float* __restrict__ bgE,
                float* __restrict__ out) {
    __shared__ float xs[2048];
    int bx = blockIdx.x;
    int tid = threadIdx.x;
    if (bx < HWA_BLOCKS) {                      // acoustic: 8 samples x 256 cols
        int bt0 = bx * 8;
        #pragma unroll
        for (int s = 0; s < 8; ++s) xs[s * 256 + tid] = pA[(size_t)(bt0 + s) * 256 + tid];
        __syncthreads();
        float p[8], g[8];
        #pragma unroll
        for (int s = 0; s < 8; ++s) { p[s] = bpA[tid]; g[s] = bgA[tid]; }
        for (int c = 0; c < 256; ++c) {
            float wp = WpTA[c * 256 + tid], wg = WgTA[c * 256 + tid];
            #pragma unroll
            for (int s = 0; s < 8; ++s) {
                float xv = xs[s * 256 + c];
                p[s] += xv * wp; g[s] += xv * wg;
            }
        }
        #pragma unroll
        for (int s = 0; s < 8; ++s) {
            float pp = fmaxf(p[s], 0.f);
            float gg = sigmf(g[s]);
            out[(size_t)(bt0 + s) * 448 + 128 + tid] = gg * pp + (1.f - gg) * xs[s * 256 + tid];
        }
    } else if (bx < HWA_BLOCKS + HWL_BLOCKS) {  // linguistic: 16 samples x 128 cols
        int bt0 = (bx - HWA_BLOCKS) * 16;
        for (int i = tid; i < 16 * 128; i += 256) xs[i] = pL[(size_t)bt0 * 128 + i];
        __syncthreads();
        int j = tid & 127, h = tid >> 7;
        float p[8], g[8];
        #pragma unroll
        for (int s = 0; s < 8; ++s) { p[s] = bpL[j]; g[s] = bgL[j]; }
        for (int c = 0; c < 128; ++c) {
            float wp = WpTL[c * 128 + j], wg = WgTL[c * 128 + j];
            #pragma unroll
            for (int s = 0; s < 8; ++s) {
                float xv = xs[(h * 8 + s) * 128 + c];
                p[s] += xv * wp; g[s] += xv * wg;
            }
        }
        #pragma unroll
        for (int s = 0; s < 8; ++s) {
            float pp = fmaxf(p[s], 0.f);
            float gg = sigmf(g[s]);
            out[(size_t)(bt0 + h * 8 + s) * 448 + j] = gg * pp + (1.f - gg) * xs[(h * 8 + s) * 128 + j];
        }
    } else {                                    // emotient: 32 samples x 64 cols
        int bt0 = (bx - HWA_BLOCKS - HWL_BLOCKS) * 32;
        for (int i = tid; i < 32 * 64; i += 256) xs[i] = pE[(size_t)bt0 * 64 + i];
        __syncthreads();
        int j = tid & 63, grp = tid >> 6;
        float p[8], g[8];
        #pragma unroll
        for (int s = 0; s < 8; ++s) { p[s] = bpE[j]; g[s] = bgE[j]; }
        for (int c = 0; c < 64; ++c) {
            float wp = WpTE[c * 64 + j], wg = WgTE[c * 64 + j];
            #pragma unroll
            for (int s = 0; s < 8; ++s) {
                float xv = xs[(grp * 8 + s) * 64 + c];
                p[s] += xv * wp; g[s] += xv * wg;
            }
        }
        #pragma unroll
        for (int s = 0; s < 8; ++s) {
            float pp = fmaxf(p[s], 0.f);
            float gg = sigmf(g[s]);
            out[(size_t)(bt0 + grp * 8 + s) * 448 + 384 + j] = gg * pp + (1.f - gg) * xs[(grp * 8 + s) * 64 + j];
        }
    }
}

// ================= fallback path (tiny workspace): slow but correct =================
__global__ __launch_bounds__(512)
void lstm_kernel_f32(const float* __restrict__ x, const int* __restrict__ lens,
                     const float* __restrict__ WihT, const float* __restrict__ WhhT,
                     const float* __restrict__ bih, const float* __restrict__ bhh,
                     float* __restrict__ hout) {
    int bt = blockIdx.x;
    int j  = threadIdx.x;
    __shared__ float xs[WE_][EE];
    __shared__ __align__(16) float hs[HH];
    __shared__ float zs[512];
    for (int idx = j; idx < WE_ * EE; idx += 512)
        ((float*)xs)[idx] = x[(size_t)bt * WE_ * EE + idx];
    if (j < HH) hs[j] = 0.f;
    float wih[EE];
    #pragma unroll
    for (int e = 0; e < EE; ++e) wih[e] = WihT[e * 512 + j];
    float whh[HH];
    #pragma unroll
    for (int h = 0; h < HH; ++h) whh[h] = WhhT[h * 512 + j];
    float bjv = bih[j] + bhh[j];
    float c_reg = 0.f;
    int len = lens[bt];
    __syncthreads();
    for (int t = 0; t < WE_; ++t) {
        float z = bjv;
        #pragma unroll
        for (int e = 0; e < EE; ++e) z += wih[e] * xs[t][e];
        const float4* h4 = (const float4*)hs;
        #pragma unroll
        for (int q = 0; q < HH / 4; ++q) {
            float4 hv = h4[q];
            z += whh[4*q+0] * hv.x + whh[4*q+1] * hv.y
               + whh[4*q+2] * hv.z + whh[4*q+3] * hv.w;
        }
        zs[j] = z;
        __syncthreads();
        if (j < HH) {
            float zi = zs[j], zf = zs[HH + j], zg = zs[2*HH + j], zo = zs[3*HH + j];
            float si = 1.f / (1.f + expf(-zi));
            float sf = 1.f / (1.f + expf(-zf));
            float so = 1.f / (1.f + expf(-zo));
            float tg = tanhf(zg);
            float c2 = sf * c_reg + si * tg;
            float h2 = so * tanhf(c2);
            bool valid = (t < len);
            float hn = valid ? h2 : hs[j];
            c_reg    = valid ? c2 : c_reg;
            hout[((size_t)bt * WE_ + t) * HH + j] = valid ? h2 : 0.f;
            hs[j] = hn;
        }
        __syncthreads();
    }
}

template<int CIN, int WIN, int COUT, int KDIM, int LOUT>
__global__ __launch_bounds__(256)
void conv_pool_simple(const float* __restrict__ x, const float* __restrict__ w,
                      const float* __restrict__ bias, float* __restrict__ pooled)
{
    constexpr int KW = KDIM / CIN;
    int bt = blockIdx.x;
    int co = blockIdx.y * 64 + (threadIdx.x & 63);
    int seg = threadIdx.x >> 6;
    __shared__ float part[4][64];
    float m = -INFINITY;
    for (int l = seg; l < LOUT; l += 4) {
        float acc = 0.f;
        for (int k = 0; k < KW; ++k) {
            const float* xr = x + ((size_t)bt * WIN + l + k) * CIN;
            const float* wr = w + ((size_t)co * CIN) * KW + k;
            for (int cc = 0; cc < CIN; ++cc) acc += xr[cc] * wr[(size_t)cc * KW];
        }
        m = fmaxf(m, acc);
    }
    part[seg][threadIdx.x & 63] = m;
    __syncthreads();
    if (threadIdx.x < 64) {
        float mm = fmaxf(fmaxf(part[0][threadIdx.x], part[1][threadIdx.x]),
                         fmaxf(part[2][threadIdx.x], part[3][threadIdx.x]));
        pooled[(size_t)bt * COUT + co] = mm + bias[co];
    }
}

// ---------------- launch ----------------
static inline int cdiv(int a, int b) { return (a + b - 1) / b; }

extern "C" void kernel_launch(void* const* d_in, const int* in_sizes, int n_in,
                              void* d_out, int out_size, void* d_ws, size_t ws_size,
                              hipStream_t stream) {
    const float* x_lin  = (const float*)d_in[0];
    const float* x_aco  = (const float*)d_in[1];
    const float* x_emo  = (const float*)d_in[2];
    const int*   wlen   = (const int*)  d_in[3];
    const float* convL_w = (const float*)d_in[5];
    const float* convL_b = (const float*)d_in[6];
    const float* convA_w = (const float*)d_in[7];
    const float* convA_b = (const float*)d_in[8];
    const float* convE_w = (const float*)d_in[9];
    const float* convE_b = (const float*)d_in[10];
    const float* hwL_Wp = (const float*)d_in[11];
    const float* hwL_bp = (const float*)d_in[12];
    const float* hwL_Wg = (const float*)d_in[13];
    const float* hwL_bg = (const float*)d_in[14];
    const float* hwA_Wp = (const float*)d_in[15];
    const float* hwA_bp = (const float*)d_in[16];
    const float* hwA_Wg = (const float*)d_in[17];
    const float* hwA_bg = (const float*)d_in[18];
    const float* hwE_Wp = (const float*)d_in[19];
    const float* hwE_bp = (const float*)d_in[20];
    const float* hwE_Wg = (const float*)d_in[21];
    const float* hwE_bg = (const float*)d_in[22];
    const float* lstm_Wih = (const float*)d_in[23];
    const float* lstm_Whh = (const float*)d_in[24];
    const float* lstm_bih = (const float*)d_in[25];
    const float* lstm_bhh = (const float*)d_in[26];
    float* out = (float*)d_out;

    // ---- workspace carve (256B aligned) ----
    char* p0 = (char*)d_ws;
    char* p = p0;
    auto alloc = [&](size_t bytes) { char* r = p; p += (bytes + 255) & ~(size_t)255; return r; };
    float* WpTL = (float*)alloc((size_t)CL * CL * 4);
    float* WgTL = (float*)alloc((size_t)CL * CL * 4);
    float* WpTA = (float*)alloc((size_t)CA * CA * 4);
    float* WgTA = (float*)alloc((size_t)CA * CA * 4);
    float* WpTE = (float*)alloc((size_t)CE * CE * 4);
    float* WgTE = (float*)alloc((size_t)CE * CE * 4);
    float* WihT = (float*)alloc((size_t)EE * 512 * 4);
    float* WhhT = (float*)alloc((size_t)HH * 512 * 4);
    unsigned short* whh_bf  = (unsigned short*)alloc((size_t)512 * 128 * 2);
    unsigned short* wihp_bf = (unsigned short*)alloc((size_t)512 * 32 * 2);
    void*  hbuf = (void*)alloc((size_t)BTOT * WE_ * HH * 4);
    float* pL   = (float*)alloc((size_t)BTOT * CL * 4);
    float* pA   = (float*)alloc((size_t)BTOT * CA * 4);
    float* pE   = (float*)alloc((size_t)BTOT * CE * 4);
    unsigned short* wtA = (unsigned short*)alloc((size_t)CA * KPA * 2);
    unsigned short* wtL = (unsigned short*)alloc((size_t)CL * KPL * 2);
    unsigned short* wtE = (unsigned short*)alloc((size_t)CE * KPE * 2);
    unsigned short* xlin_p = (unsigned short*)alloc((size_t)BTOT * WL_ * ELP * 2 + 64);
    unsigned short* xaco_p = (unsigned short*)alloc((size_t)BTOT * WA_ * EAP * 2 + 64);
    size_t need = (size_t)(p - p0);
    bool big = ws_size >= need;

    if (big) {
        prep_all<true><<<2048, 256, 0, stream>>>(hwL_Wp, WpTL, hwL_Wg, WgTL, hwA_Wp, WpTA, hwA_Wg, WgTA,
                                                 hwE_Wp, WpTE, hwE_Wg, WgTE, lstm_Wih, WihT, lstm_Whh, WhhT,
                                                 convL_w, wtL, convE_w, wtE, convA_w, wtA, whh_bf, wihp_bf);
        lstm_cvt<<<LSTM_BLOCKS + CVT_BLOCKS, 512, 0, stream>>>(
            x_emo, wihp_bf, whh_bf, lstm_bih, lstm_bhh, wlen, (unsigned short*)hbuf,
            x_aco, x_lin, xaco_p, xlin_p);
        conv_all<<<1536, 256, 0, stream>>>(xaco_p, wtA, convA_b, pA,
                                           xlin_p, wtL, convL_b, pL,
                                           (const unsigned short*)hbuf, wtE, convE_b, pE);
        highway_v2<<<HWA_BLOCKS + HWL_BLOCKS + HWE_BLOCKS, 256, 0, stream>>>(
            pL, pA, pE, WpTL, hwL_bp, WgTL, hwL_bg, WpTA, hwA_bp, WgTA, hwA_bg,
            WpTE, hwE_bp, WgTE, hwE_bg, out);
    } else {
        prep_all<false><<<2048, 256, 0, stream>>>(hwL_Wp, WpTL, hwL_Wg, WgTL, hwA_Wp, WpTA, hwA_Wg, WgTA,
                                                  hwE_Wp, WpTE, hwE_Wg, WgTE, lstm_Wih, WihT, lstm_Whh, WhhT,
                                                  convL_w, wtL, convE_w, wtE, convA_w, wtA, whh_bf, wihp_bf);
        lstm_kernel_f32<<<BTOT, 512, 0, stream>>>(x_emo, wlen, WihT, WhhT, lstm_bih, lstm_bhh, (float*)hbuf);
        conv_pool_simple<EA, WA_, CA, KDIMA, LOUTA>
            <<<dim3(BTOT, CA / 64), 256, 0, stream>>>(x_aco, convA_w, convA_b, pA);
        conv_pool_simple<EL, WL_, CL, KDIML, LOUTL>
            <<<dim3(BTOT, CL / 64), 256, 0, stream>>>(x_lin, convL_w, convL_b, pL);
        conv_pool_simple<HH, WE_, CE, KDIME, LOUTE>
            <<<dim3(BTOT, CE / 64), 256, 0, stream>>>((const float*)hbuf, convE_w, convE_b, pE);
        highway_v2<<<HWA_BLOCKS + HWL_BLOCKS + HWE_BLOCKS, 256, 0, stream>>>(
            pL, pA, pE, WpTL, hwL_bp, WgTL, hwL_bg, WpTA, hwA_bp, WgTA, hwA_bg,
            WpTE, hwE_bp, WgTE, hwE_bg, out);
    }
}

// Round 15
// 507.036 us; speedup vs baseline: 1.7155x; 1.0554x over previous
//
#include <hip/hip_runtime.h>
#include <hip/hip_bf16.h>
#include <math.h>

// ---------------- problem dims (fixed by setup_inputs) ----------------
#define BTOT 1536            // B*T = 32*48
// linguistic
#define EL 300
#define ELP 320              // padded CIN (10 c-chunks of 32)
#define WL_ 33
#define CL 128
#define LOUTL 29
#define KPL 1600
// acoustic
#define EA 988
#define EAP 992              // 31 c-chunks
#define WA_ 50
#define CA 256
#define LOUTA 41
#define KPA 9920
// emotient
#define EE 20
#define WE_ 30
#define HH 128
#define CE 64
#define LOUTE 28
#define KPE 384
// fallback K dims
#define KDIML 1500
#define KDIMA 9880
#define KDIME 384

typedef __attribute__((ext_vector_type(4))) float f32x4;
typedef __attribute__((ext_vector_type(8))) short short8;

// RNE float->bf16 (inputs finite)
__device__ __forceinline__ unsigned short f2bf(float f) {
    unsigned int x = __float_as_uint(f);
    unsigned int r = (x + 0x7fffu + ((x >> 16) & 1u)) >> 16;
    return (unsigned short)r;
}

__device__ __forceinline__ float sigmf(float x) {
    return __builtin_amdgcn_rcpf(1.f + __expf(-x));
}
__device__ __forceinline__ float tanh_fast(float x) {
    return 1.f - 2.f * __builtin_amdgcn_rcpf(1.f + __expf(2.f * x));
}

#define GLD16(gp, lp) __builtin_amdgcn_global_load_lds( \
    (const __attribute__((address_space(1))) void*)(gp), \
    (__attribute__((address_space(3))) void*)(lp), 16, 0, 0)

template<int N> __device__ __forceinline__ void vmwait() {
    if constexpr (N == 0) asm volatile("s_waitcnt vmcnt(0)" ::: "memory");
    else if constexpr (N == 1) asm volatile("s_waitcnt vmcnt(1)" ::: "memory");
    else if constexpr (N == 2) asm volatile("s_waitcnt vmcnt(2)" ::: "memory");
    else if constexpr (N == 3) asm volatile("s_waitcnt vmcnt(3)" ::: "memory");
    else if constexpr (N == 4) asm volatile("s_waitcnt vmcnt(4)" ::: "memory");
    else if constexpr (N == 6) asm volatile("s_waitcnt vmcnt(6)" ::: "memory");
    else if constexpr (N == 8) asm volatile("s_waitcnt vmcnt(8)" ::: "memory");
    else static_assert(N == 0, "add case");
}

// ---------------- small helpers ----------------
__device__ __forceinline__ void tr_one(const float* a, float* at, int R, int C, int idx) {
    int r = idx / C, c = idx - r * C;
    at[c * R + r] = a[idx];
}
template<int CIN, int CINP, int KW, int COUT, int KPAD>
__device__ __forceinline__ void wt_one(const float* w, unsigned short* wt, int idx) {
    int co = idx / KPAD;
    int p  = idx - co * KPAD;
    int k  = p / CINP;
    int c  = p - k * CINP;
    float v = 0.f;
    if (k < KW && c < CIN) v = w[(co * CIN + c) * KW + k];
    wt[idx] = f2bf(v);
}
template<int CIN, int CINP>
__device__ __forceinline__ void cvt_chunk(const float* in, unsigned short* out, int idx) {
    constexpr int CH = CINP / 8;
    int row = idx / CH, c0 = (idx - row * CH) * 8;
    const float* src = in + (size_t)row * CIN + c0;
    union { short8 s; unsigned short u[8]; } o;
    if (c0 + 8 <= CIN) {
        float4 v0 = *(const float4*)src;
        float4 v1 = *(const float4*)(src + 4);
        o.u[0]=f2bf(v0.x); o.u[1]=f2bf(v0.y); o.u[2]=f2bf(v0.z); o.u[3]=f2bf(v0.w);
        o.u[4]=f2bf(v1.x); o.u[5]=f2bf(v1.y); o.u[6]=f2bf(v1.z); o.u[7]=f2bf(v1.w);
    } else {
        #pragma unroll
        for (int j = 0; j < 8; ++j) o.u[j] = (c0 + j < CIN) ? f2bf(src[j]) : (unsigned short)0;
    }
    *(short8*)(out + (size_t)row * CINP + c0) = o.s;
}

// ================= prep_cvt (big path): all weight prep + BOTH input converts, high-occupancy =================
__global__ void prep_cvt(const float* hwL_Wp, float* WpTL, const float* hwL_Wg, float* WgTL,
                         const float* hwA_Wp, float* WpTA, const float* hwA_Wg, float* WgTA,
                         const float* hwE_Wp, float* WpTE, const float* hwE_Wg, float* WgTE,
                         const float* lstm_Wih, const float* lstm_Whh,
                         const float* convL_w, unsigned short* wtL,
                         const float* convE_w, unsigned short* wtE,
                         const float* convA_w, unsigned short* wtA,
                         unsigned short* whh_bf, unsigned short* wihp_bf,
                         const float* xa, const float* xl,
                         unsigned short* outa, unsigned short* outl) {
    constexpr int NAC = (BTOT * WA_) * (EAP / 8);
    constexpr int NLC = (BTOT * WL_) * (ELP / 8);
    constexpr int S1 = 16384, S2 = 16384, S3 = 65536, S4 = 65536, S5 = 4096, S6 = 4096;
    constexpr int S9 = 128 * KPL, S10 = 64 * KPE, S11 = 512 * 128, S12 = 512 * 32;
    constexpr int S13 = CA * KPA;
    constexpr int TOTAL = NAC + NLC + S1 + S2 + S3 + S4 + S5 + S6 + S9 + S10 + S11 + S12 + S13;
    int stride = gridDim.x * blockDim.x;
    for (int i = blockIdx.x * blockDim.x + threadIdx.x; i < TOTAL; i += stride) {
        int idx = i;
        if (idx < NAC) { cvt_chunk<EA, EAP>(xa, outa, idx); continue; } idx -= NAC;
        if (idx < NLC) { cvt_chunk<EL, ELP>(xl, outl, idx); continue; } idx -= NLC;
        if (idx < S1) { tr_one(hwL_Wp, WpTL, 128, 128, idx); continue; } idx -= S1;
        if (idx < S2) { tr_one(hwL_Wg, WgTL, 128, 128, idx); continue; } idx -= S2;
        if (idx < S3) { tr_one(hwA_Wp, WpTA, 256, 256, idx); continue; } idx -= S3;
        if (idx < S4) { tr_one(hwA_Wg, WgTA, 256, 256, idx); continue; } idx -= S4;
        if (idx < S5) { tr_one(hwE_Wp, WpTE, 64, 64, idx); continue; } idx -= S5;
        if (idx < S6) { tr_one(hwE_Wg, WgTE, 64, 64, idx); continue; } idx -= S6;
        if (idx < S9) { wt_one<EL, ELP, 5, CL, KPL>(convL_w, wtL, idx); continue; } idx -= S9;
        if (idx < S10) { wt_one<HH, HH, 3, CE, KPE>(convE_w, wtE, idx); continue; } idx -= S10;
        if (idx < S11) { whh_bf[idx] = f2bf(lstm_Whh[idx]); continue; } idx -= S11;
        if (idx < S12) { int col = idx >> 5, e = idx & 31;
                         wihp_bf[idx] = (e < 20) ? f2bf(lstm_Wih[col * 20 + e]) : (unsigned short)0;
                         continue; } idx -= S12;
        wt_one<EA, EAP, 10, CA, KPA>(convA_w, wtA, idx);
    }
}

// ================= lstm_only: 16 samples/block, 96 blocks (proven r12/r14 LSTM path) =================
#define LSTM_BLOCKS 96

__global__ __launch_bounds__(512, 1)
void lstm_only(const float* __restrict__ x_emo,
               const unsigned short* __restrict__ wihp_bf, const unsigned short* __restrict__ whh_bf,
               const float* __restrict__ bih, const float* __restrict__ bhh,
               const int* __restrict__ lens, unsigned short* __restrict__ hbuf)
{
    __shared__ __align__(16) unsigned short xq[WE_ * 16 * 32];  // 30 KB
    __shared__ __align__(16) char h_s[2 * 16 * HH * 2];         // 8 KB dbuf, swizzled

    const int tid  = threadIdx.x;
    const int w    = tid >> 6;
    const int lane = tid & 63;
    const int lr   = lane & 15;
    const int lq   = lane >> 4;
    const int s0   = blockIdx.x * 16;
    const int c    = w * 16 + lr;     // gate-col within 128

    short8 bfr[4][4];
    short8 bw[4];
    float bj[4];
    #pragma unroll
    for (int g = 0; g < 4; ++g) {
        int col = g * 128 + c;
        #pragma unroll
        for (int kt = 0; kt < 4; ++kt)
            bfr[g][kt] = *(const short8*)(whh_bf + (size_t)col * 128 + kt * 32 + lq * 8);
        bw[g] = *(const short8*)(wihp_bf + (size_t)col * 32 + lq * 8);
        bj[g] = bih[col] + bhh[col];
    }
    int len4[4];
    #pragma unroll
    for (int j = 0; j < 4; ++j) len4[j] = lens[s0 + lq * 4 + j];

    for (int i = tid; i < WE_ * 16 * 32; i += 512) {
        int t = i >> 9, r = (i >> 5) & 15, e = i & 31;
        xq[i] = (e < 20) ? f2bf(x_emo[(((size_t)(s0 + r) * WE_) + t) * 20 + e]) : (unsigned short)0;
    }
    for (int i = tid; i < 2048; i += 512) ((unsigned int*)h_s)[i] = 0u;

    float c_prev[4] = {0.f, 0.f, 0.f, 0.f};
    unsigned short hb_prev[4] = {0, 0, 0, 0};
    __syncthreads();

    for (int t = 0; t < WE_; ++t) {
        const char* hsr = h_s + (t & 1) * 4096;
        char* hsw = h_s + ((t & 1) ^ 1) * 4096;
        short8 ax = *(const short8*)((const char*)xq + (size_t)(t * 16 + lr) * 64 + lq * 16);
        short8 af[4];
        #pragma unroll
        for (int kt = 0; kt < 4; ++kt)
            af[kt] = *(const short8*)(hsr + ((lr * 256 + kt * 64 + lq * 16) ^ ((lr & 7) << 4)));
        f32x4 acc[4];
        #pragma unroll
        for (int g = 0; g < 4; ++g)
            acc[g] = __builtin_amdgcn_mfma_f32_16x16x32_bf16(ax, bw[g], (f32x4){0.f,0.f,0.f,0.f}, 0, 0, 0);
        #pragma unroll
        for (int kt = 0; kt < 4; ++kt)
            #pragma unroll
            for (int g = 0; g < 4; ++g)
                acc[g] = __builtin_amdgcn_mfma_f32_16x16x32_bf16(af[kt], bfr[g][kt], acc[g], 0, 0, 0);
        #pragma unroll
        for (int j = 0; j < 4; ++j) {
            int s = lq * 4 + j;
            float zi = acc[0][j] + bj[0];
            float zf = acc[1][j] + bj[1];
            float zg = acc[2][j] + bj[2];
            float zo = acc[3][j] + bj[3];
            float si = sigmf(zi), sf = sigmf(zf), so = sigmf(zo);
            float tg = tanh_fast(zg);
            float c2 = sf * c_prev[j] + si * tg;
            float h2 = so * tanh_fast(c2);
            bool valid = (t < len4[j]);
            c_prev[j] = valid ? c2 : c_prev[j];
            unsigned short h2b = f2bf(h2);
            unsigned short hn = valid ? h2b : hb_prev[j];
            hb_prev[j] = hn;
            *(unsigned short*)(hsw + (((s * HH + c) * 2) ^ ((s & 7) << 4))) = hn;
            hbuf[(((size_t)(s0 + s) * WE_) + t) * HH + c] = valid ? h2b : (unsigned short)0;
        }
        __syncthreads();
    }
}

// ================= conv bodies (device functions; proven r10/r11 schedules) =================
template<int LOUT, int WIN, int CINP, int KW, int BN, int MFR, int COUT>
__device__ __forceinline__
void conv_body_v10(char* smem, int m, int n,
                   const unsigned short* __restrict__ xb, const unsigned short* __restrict__ wt,
                   const float* __restrict__ bias, float* __restrict__ pooled)
{
    constexpr int CCH   = CINP / 32;
    constexpr int KB    = CINP * 2;
    constexpr int KTOTB = CINP * KW * 2;
    constexpr int NFR   = BN / 16;
    constexpr int B_IT  = BN / 64;
    constexpr int ABUF  = 4 * 64 * 64;
    constexpr int BBUF  = BN * 64;

    const int tid  = threadIdx.x;
    const int lane = tid & 63;
    const int wid  = tid >> 6;
    const int lr   = lane & 15;
    const int lq   = lane >> 4;
    const int lq16 = lq * 16;

    f32x4 acc[MFR][NFR];
    #pragma unroll
    for (int i = 0; i < MFR; ++i)
        #pragma unroll
        for (int j = 0; j < NFR; ++j) acc[i][j] = (f32x4){0.f, 0.f, 0.f, 0.f};

    const int aw_r = tid >> 2;
    const int aw   = (aw_r < WIN) ? aw_r : (WIN - 1);
    const int slot = tid & 3;
    const char* asrc[4];
    #pragma unroll
    for (int i = 0; i < 4; ++i)
        asrc[i] = (const char*)xb + ((size_t)((m * 4 + i) * WIN + aw)) * KB
                + ((slot * 16) ^ (((aw_r >> 1) & 3) << 4));
    const char* bsrc[B_IT];
    #pragma unroll
    for (int i = 0; i < B_IT; ++i) {
        int col = (tid + i * 256) >> 2;
        bsrc[i] = (const char*)wt + (size_t)(n * BN + col) * KTOTB
                + ((slot * 16) ^ (((col >> 1) & 3) << 4));
    }

    char* const abuf0 = smem;
    char* const abuf1 = smem + ABUF;
    char* const bbase = smem + 2 * ABUF;

    int cbo[NFR];
    #pragma unroll
    for (int nf = 0; nf < NFR; ++nf) {
        int cb = nf * 16 + lr;
        cbo[nf] = cb * 64 + (lq16 ^ (((cb >> 1) & 3) << 4));
    }

    #pragma unroll
    for (int i = 0; i < 4; ++i)
        GLD16(asrc[i], abuf0 + i * 4096 + tid * 16);
    #pragma unroll
    for (int s = 0; s < 3; ++s)
        #pragma unroll
        for (int i = 0; i < B_IT; ++i)
            GLD16(bsrc[i] + s * KB, bbase + s * BBUF + i * 4096 + tid * 16);
    vmwait<0>();
    __builtin_amdgcn_s_barrier();

    int bcur = 0;

#define STEP(KK, WN, TAIL) do {                                                    \
    const char* bb = bbase + bcur * BBUF;                                          \
    short8 afr[MFR];                                                               \
    _Pragma("unroll")                                                              \
    for (int o = 0; o < MFR; ++o) {                                                \
        int row = o * 16 + lr + (KK);                                              \
        afr[o] = *(const short8*)(awave + row * 64 + (lq16 ^ (((row >> 1) & 3) << 4))); \
    }                                                                              \
    short8 bf[NFR];                                                                \
    _Pragma("unroll")                                                              \
    for (int nf = 0; nf < NFR; ++nf) bf[nf] = *(const short8*)(bb + cbo[nf]);      \
    if (!(TAIL) || (KK) < KW - 3) {                                                \
        constexpr int k3_ = ((KK) + 3 < KW) ? (KK) + 3 : (KK) + 3 - KW;            \
        int boff = k3_ * KB + (((KK) + 3 < KW) ? ci : ci + 1) * 64;                \
        char* bstg = bbase + ((bcur + 3) & 3) * BBUF;                              \
        _Pragma("unroll")                                                          \
        for (int i = 0; i < B_IT; ++i)                                             \
            GLD16(bsrc[i] + boff, bstg + i * 4096 + tid * 16);                     \
    }                                                                              \
    if (!(TAIL)) {                                                                 \
        if ((KK) == 0) {                                                           \
            _Pragma("unroll")                                                      \
            for (int i = 0; i < 4; ++i)                                            \
                GLD16(asrc[i] + (size_t)(ci + 1) * 64, abn + i * 4096 + tid * 16); \
        }                                                                          \
    }                                                                              \
    __builtin_amdgcn_s_setprio(1);                                                 \
    _Pragma("unroll")                                                              \
    for (int nf = 0; nf < NFR; ++nf)                                               \
        _Pragma("unroll")                                                          \
        for (int o = 0; o < MFR; ++o)                                              \
            acc[o][nf] = __builtin_amdgcn_mfma_f32_16x16x32_bf16(afr[o], bf[nf], acc[o][nf], 0, 0, 0); \
    __builtin_amdgcn_s_setprio(0);                                                 \
    vmwait<WN>();                                                                  \
    asm volatile("" ::: "memory");                                                 \
    __builtin_amdgcn_s_barrier();                                                  \
    bcur = (bcur + 1) & 3;                                                         \
} while (0)

    for (int ci = 0; ci < CCH - 1; ++ci) {
        const char* ab = (ci & 1) ? abuf1 : abuf0;
        char* abn = (ci & 1) ? abuf0 : abuf1;
        const char* awave = ab + wid * 4096;
        if constexpr (KW == 5) {
            STEP(0, 8, false); STEP(1, 8, false); STEP(2, 4, false); STEP(3, 4, false); STEP(4, 4, false);
        } else {
            STEP(0, 6, false); STEP(1, 6, false); STEP(2, 2, false);
        }
    }
    {
        const int ci = CCH - 1;
        const char* ab = (ci & 1) ? abuf1 : abuf0;
        char* abn = (ci & 1) ? abuf0 : abuf1; (void)abn;
        const char* awave = ab + wid * 4096;
        if constexpr (KW == 5) {
            STEP(0, 4, true); STEP(1, 4, true); STEP(2, 2, true); STEP(3, 0, true); STEP(4, 0, true);
        } else {
            STEP(0, 1, true); STEP(1, 0, true); STEP(2, 0, true);
        }
    }
#undef STEP

    const int bt = m * 4 + wid;
    #pragma unroll
    for (int nf = 0; nf < NFR; ++nf) {
        float mx = -INFINITY;
        #pragma unroll
        for (int o = 0; o < MFR; ++o) {
            int rb = o * 16 + lq * 4;
            #pragma unroll
            for (int j = 0; j < 4; ++j)
                if (rb + j < LOUT) mx = fmaxf(mx, acc[o][nf][j]);
        }
        mx = fmaxf(mx, __shfl_xor(mx, 16, 64));
        mx = fmaxf(mx, __shfl_xor(mx, 32, 64));
        if (lane < 16) {
            int col = n * BN + nf * 16 + lane;
            pooled[(size_t)bt * COUT + col] = mx + bias[col];
        }
    }
}

// conv_a body (r11): pair barriers, 5-slot B ring, late A staging (k5..k8)
__device__ __forceinline__
void conv_body_a(char* smem, int m, int n,
                 const unsigned short* __restrict__ xb, const unsigned short* __restrict__ wt,
                 const float* __restrict__ bias, float* __restrict__ pooled)
{
    constexpr int LOUT = LOUTA, WIN = WA_, CINP = EAP, BN = 128, COUT = CA;
    constexpr int CCH  = CINP / 32;        // 31
    constexpr int KB   = CINP * 2;         // 1984
    constexpr int KTOTB = CINP * 10 * 2;
    constexpr int ABUF = 4 * 64 * 64;      // 16 KB
    constexpr int BBUF = BN * 64;          // 8 KB

    const int tid  = threadIdx.x;
    const int lane = tid & 63;
    const int wid  = tid >> 6;
    const int lr   = lane & 15;
    const int lq   = lane >> 4;
    const int lq16 = lq * 16;

    f32x4 acc[3][8];
    #pragma unroll
    for (int i = 0; i < 3; ++i)
        #pragma unroll
        for (int j = 0; j < 8; ++j) acc[i][j] = (f32x4){0.f, 0.f, 0.f, 0.f};

    const int aw_r = tid >> 2;
    const int aw   = (aw_r < WIN) ? aw_r : (WIN - 1);
    const int slot = tid & 3;
    const char* asrc[4];
    #pragma unroll
    for (int i = 0; i < 4; ++i)
        asrc[i] = (const char*)xb + ((size_t)((m * 4 + i) * WIN + aw)) * KB
                + ((slot * 16) ^ (((aw_r >> 1) & 3) << 4));
    const char* bsrc[2];
    #pragma unroll
    for (int i = 0; i < 2; ++i) {
        int col = (tid + i * 256) >> 2;
        bsrc[i] = (const char*)wt + (size_t)(n * BN + col) * KTOTB
                + ((slot * 16) ^ (((col >> 1) & 3) << 4));
    }

    char* const abuf0 = smem;
    char* const abuf1 = smem + ABUF;
    char* const bbase = smem + 2 * ABUF;

    int cbo[8];
    #pragma unroll
    for (int nf = 0; nf < 8; ++nf) {
        int cb = nf * 16 + lr;
        cbo[nf] = cb * 64 + (lq16 ^ (((cb >> 1) & 3) << 4));
    }

    #pragma unroll
    for (int i = 0; i < 4; ++i)
        GLD16(asrc[i], abuf0 + i * 4096 + tid * 16);
    #pragma unroll
    for (int s = 0; s < 3; ++s) {
        GLD16(bsrc[0] + s * KB, bbase + s * BBUF + tid * 16);
        GLD16(bsrc[1] + s * KB, bbase + s * BBUF + 4096 + tid * 16);
    }
    vmwait<0>();
    __builtin_amdgcn_s_barrier();

    int bcur = 0;

#define VSTEP(KK, DOA, DOBAR, WN, DOBSTG, CHN) do {                                \
    const char* bb = bbase + bcur * BBUF;                                          \
    short8 afr[3];                                                                 \
    _Pragma("unroll")                                                              \
    for (int o = 0; o < 3; ++o) {                                                  \
        int row = o * 16 + lr + (KK);                                              \
        afr[o] = *(const short8*)(awave + row * 64 + (lq16 ^ (((row >> 1) & 3) << 4))); \
    }                                                                              \
    short8 bf[8];                                                                  \
    _Pragma("unroll")                                                              \
    for (int nf = 0; nf < 8; ++nf) bf[nf] = *(const short8*)(bb + cbo[nf]);        \
    if (DOBSTG) {                                                                  \
        constexpr int K3 = ((KK) + 3 < 10) ? (KK) + 3 : (KK) - 7;                  \
        int boff = K3 * KB + (CHN) * 64;                                           \
        int b3 = bcur + 3; if (b3 >= 5) b3 -= 5;                                   \
        char* bstg = bbase + b3 * BBUF;                                            \
        GLD16(bsrc[0] + boff, bstg + tid * 16);                                    \
        GLD16(bsrc[1] + boff, bstg + 4096 + tid * 16);                             \
    }                                                                              \
    if (DOA) GLD16(asrc[(KK) - 5] + (size_t)(ci + 1) * 64,                         \
                   abn + ((KK) - 5) * 4096 + tid * 16);                            \
    __builtin_amdgcn_s_setprio(1);                                                 \
    _Pragma("unroll")                                                              \
    for (int nf = 0; nf < 8; ++nf)                                                 \
        _Pragma("unroll")                                                          \
        for (int o = 0; o < 3; ++o)                                                \
            acc[o][nf] = __builtin_amdgcn_mfma_f32_16x16x32_bf16(afr[o], bf[nf], acc[o][nf], 0, 0, 0); \
    __builtin_amdgcn_s_setprio(0);                                                 \
    if (DOBAR) { vmwait<WN>(); asm volatile("" ::: "memory");                      \
                 __builtin_amdgcn_s_barrier(); }                                   \
    bcur = (bcur == 4) ? 0 : bcur + 1;                                             \
} while (0)

    for (int ci = 0; ci < CCH - 1; ++ci) {
        const char* ab = (ci & 1) ? abuf1 : abuf0;
        char* abn = (ci & 1) ? abuf0 : abuf1;
        const char* awave = ab + wid * 4096;
        VSTEP(0, false, false, 0, true, ci);
        VSTEP(1, false, true,  2, true, ci);
        VSTEP(2, false, false, 0, true, ci);
        VSTEP(3, false, true,  2, true, ci);
        VSTEP(4, false, false, 0, true, ci);
        VSTEP(5, true,  true,  3, true, ci);
        VSTEP(6, true,  false, 0, true, ci);
        VSTEP(7, true,  true,  3, true, ci + 1);
        VSTEP(8, true,  false, 0, true, ci + 1);
        VSTEP(9, false, true,  2, true, ci + 1);
    }
    {
        const int ci = CCH - 1;
        const char* ab = (ci & 1) ? abuf1 : abuf0;
        char* abn = (ci & 1) ? abuf0 : abuf1; (void)abn;
        const char* awave = ab + wid * 4096;
        VSTEP(0, false, false, 0, true,  ci);
        VSTEP(1, false, true,  2, true,  ci);
        VSTEP(2, false, false, 0, true,  ci);
        VSTEP(3, false, true,  2, true,  ci);
        VSTEP(4, false, false, 0, true,  ci);
        VSTEP(5, false, true,  2, true,  ci);
        VSTEP(6, false, false, 0, true,  ci);
        VSTEP(7, false, true,  0, false, ci);
        VSTEP(8, false, false, 0, false, ci);
        VSTEP(9, false, true,  0, false, ci);
    }
#undef VSTEP

    const int bt = m * 4 + wid;
    #pragma unroll
    for (int nf = 0; nf < 8; ++nf) {
        float mx = -INFINITY;
        #pragma unroll
        for (int o = 0; o < 3; ++o) {
            int rb = o * 16 + lq * 4;
            #pragma unroll
            for (int j = 0; j < 4; ++j)
                if (rb + j < LOUT) mx = fmaxf(mx, acc[o][nf][j]);
        }
        mx = fmaxf(mx, __shfl_xor(mx, 16, 64));
        mx = fmaxf(mx, __shfl_xor(mx, 32, 64));
        if (lane < 16) {
            int col = n * BN + nf * 16 + lane;
            pooled[(size_t)bt * COUT + col] = mx + bias[col];
        }
    }
}

// ================= mega conv launch: A [0,768) + L [768,1152) + E [1152,1536) =================
#define CONVA_BLOCKS 768
#define CONVL_BLOCKS 384
__global__ __launch_bounds__(256, 2)
void conv_all(const unsigned short* __restrict__ xaco_p, const unsigned short* __restrict__ wtA,
              const float* __restrict__ convA_b, float* __restrict__ pA,
              const unsigned short* __restrict__ xlin_p, const unsigned short* __restrict__ wtL,
              const float* __restrict__ convL_b, float* __restrict__ pL,
              const unsigned short* __restrict__ hbuf, const unsigned short* __restrict__ wtE,
              const float* __restrict__ convE_b, float* __restrict__ pE)
{
    __shared__ __align__(16) char smem[73728];
    int bx = blockIdx.x;
    if (bx < CONVA_BLOCKS) {
        int xcd = bx & 7;
        int n = xcd & 1;
        int m = (xcd >> 1) * 96 + (bx >> 3);
        conv_body_a(smem, m, n, xaco_p, wtA, convA_b, pA);
    } else if (bx < CONVA_BLOCKS + CONVL_BLOCKS) {
        conv_body_v10<LOUTL, WL_, ELP, 5, 128, 2, CL>(smem, bx - CONVA_BLOCKS, 0,
                                                      xlin_p, wtL, convL_b, pL);
    } else {
        conv_body_v10<LOUTE, WE_, HH, 3, 64, 2, CE>(smem, bx - CONVA_BLOCKS - CONVL_BLOCKS, 0,
                                                    hbuf, wtE, convE_b, pE);
    }
}

// ---------------- fused highway v2: sample-batched (A:8/blk, L:16/blk, E:32/blk) ----------------
#define HWA_BLOCKS 192
#define HWL_BLOCKS 96
#define HWE_BLOCKS 48
__global__ __launch_bounds__(256)
void highway_v2(const float* __restrict__ pL, const float* __restrict__ pA, const float* __restrict__ pE,
                const float* __restrict__ WpTL, const float* __restrict__ bpL,
                const float* __restrict__ WgTL, const float* __restrict__ bgL,
                const float* __restrict__ WpTA, const float* __restrict__ bpA,
                const float* __restrict__ WgTA, const float* __restrict__ bgA,
                const float* __restrict__ WpTE, const float* __restrict__ bpE,
                const float* __restrict__ WgTE, const float* __restrict__ bgE,
                float* __restrict__ out) {
    __shared__ float xs[2048];
    int bx = blockIdx.x;
    int tid = threadIdx.x;
    if (bx < HWA_BLOCKS) {                      // acoustic: 8 samples x 256 cols
        int bt0 = bx * 8;
        #pragma unroll
        for (int s = 0; s < 8; ++s) xs[s * 256 + tid] = pA[(size_t)(bt0 + s) * 256 + tid];
        __syncthreads();
        float p[8], g[8];
        #pragma unroll
        for (int s = 0; s < 8; ++s) { p[s] = bpA[tid]; g[s] = bgA[tid]; }
        for (int c = 0; c < 256; ++c) {
            float wp = WpTA[c * 256 + tid], wg = WgTA[c * 256 + tid];
            #pragma unroll
            for (int s = 0; s < 8; ++s) {
                float xv = xs[s * 256 + c];
                p[s] += xv * wp; g[s] += xv * wg;
            }
        }
        #pragma unroll
        for (int s = 0; s < 8; ++s) {
            float pp = fmaxf(p[s], 0.f);
            float gg = sigmf(g[s]);
            out[(size_t)(bt0 + s) * 448 + 128 + tid] = gg * pp + (1.f - gg) * xs[s * 256 + tid];
        }
    } else if (bx < HWA_BLOCKS + HWL_BLOCKS) {  // linguistic: 16 samples x 128 cols
        int bt0 = (bx - HWA_BLOCKS) * 16;
        for (int i = tid; i < 16 * 128; i += 256) xs[i] = pL[(size_t)bt0 * 128 + i];
        __syncthreads();
        int j = tid & 127, h = tid >> 7;
        float p[8], g[8];
        #pragma unroll
        for (int s = 0; s < 8; ++s) { p[s] = bpL[j]; g[s] = bgL[j]; }
        for (int c = 0; c < 128; ++c) {
            float wp = WpTL[c * 128 + j], wg = WgTL[c * 128 + j];
            #pragma unroll
            for (int s = 0; s < 8; ++s) {
                float xv = xs[(h * 8 + s) * 128 + c];
                p[s] += xv * wp; g[s] += xv * wg;
            }
        }
        #pragma unroll
        for (int s = 0; s < 8; ++s) {
            float pp = fmaxf(p[s], 0.f);
            float gg = sigmf(g[s]);
            out[(size_t)(bt0 + h * 8 + s) * 448 + j] = gg * pp + (1.f - gg) * xs[(h * 8 + s) * 128 + j];
        }
    } else {                                    // emotient: 32 samples x 64 cols
        int bt0 = (bx - HWA_BLOCKS - HWL_BLOCKS) * 32;
        for (int i = tid; i < 32 * 64; i += 256) xs[i] = pE[(size_t)bt0 * 64 + i];
        __syncthreads();
        int j = tid & 63, grp = tid >> 6;
        float p[8], g[8];
        #pragma unroll
        for (int s = 0; s < 8; ++s) { p[s] = bpE[j]; g[s] = bgE[j]; }
        for (int c = 0; c < 64; ++c) {
            float wp = WpTE[c * 64 + j], wg = WgTE[c * 64 + j];
            #pragma unroll
            for (int s = 0; s < 8; ++s) {
                float xv = xs[(grp * 8 + s) * 64 + c];
                p[s] += xv * wp; g[s] += xv * wg;
            }
        }
        #pragma unroll
        for (int s = 0; s < 8; ++s) {
            float pp = fmaxf(p[s], 0.f);
            float gg = sigmf(g[s]);
            out[(size_t)(bt0 + grp * 8 + s) * 448 + 384 + j] = gg * pp + (1.f - gg) * xs[(grp * 8 + s) * 64 + j];
        }
    }
}

// ================= fallback path (tiny workspace): slow but correct =================
__global__ void prep_fallback(const float* hwL_Wp, float* WpTL, const float* hwL_Wg, float* WgTL,
                              const float* hwA_Wp, float* WpTA, const float* hwA_Wg, float* WgTA,
                              const float* hwE_Wp, float* WpTE, const float* hwE_Wg, float* WgTE,
                              const float* lstm_Wih, float* WihT, const float* lstm_Whh, float* WhhT) {
    constexpr int S1 = 16384, S2 = 16384, S3 = 65536, S4 = 65536, S5 = 4096, S6 = 4096;
    constexpr int S7 = 512 * 20, S8 = 512 * 128;
    constexpr int TOTAL = S1 + S2 + S3 + S4 + S5 + S6 + S7 + S8;
    int stride = gridDim.x * blockDim.x;
    for (int i = blockIdx.x * blockDim.x + threadIdx.x; i < TOTAL; i += stride) {
        int idx = i;
        if (idx < S1) { tr_one(hwL_Wp, WpTL, 128, 128, idx); continue; } idx -= S1;
        if (idx < S2) { tr_one(hwL_Wg, WgTL, 128, 128, idx); continue; } idx -= S2;
        if (idx < S3) { tr_one(hwA_Wp, WpTA, 256, 256, idx); continue; } idx -= S3;
        if (idx < S4) { tr_one(hwA_Wg, WgTA, 256, 256, idx); continue; } idx -= S4;
        if (idx < S5) { tr_one(hwE_Wp, WpTE, 64, 64, idx); continue; } idx -= S5;
        if (idx < S6) { tr_one(hwE_Wg, WgTE, 64, 64, idx); continue; } idx -= S6;
        if (idx < S7) { tr_one(lstm_Wih, WihT, 512, 20, idx); continue; } idx -= S7;
        tr_one(lstm_Whh, WhhT, 512, 128, idx);
    }
}

__global__ __launch_bounds__(512)
void lstm_kernel_f32(const float* __restrict__ x, const int* __restrict__ lens,
                     const float* __restrict__ WihT, const float* __restrict__ WhhT,
                     const float* __restrict__ bih, const float* __restrict__ bhh,
                     float* __restrict__ hout) {
    int bt = blockIdx.x;
    int j  = threadIdx.x;
    __shared__ float xs[WE_][EE];
    __shared__ __align__(16) float hs[HH];
    __shared__ float zs[512];
    for (int idx = j; idx < WE_ * EE; idx += 512)
        ((float*)xs)[idx] = x[(size_t)bt * WE_ * EE + idx];
    if (j < HH) hs[j] = 0.f;
    float wih[EE];
    #pragma unroll
    for (int e = 0; e < EE; ++e) wih[e] = WihT[e * 512 + j];
    float whh[HH];
    #pragma unroll
    for (int h = 0; h < HH; ++h) whh[h] = WhhT[h * 512 + j];
    float bjv = bih[j] + bhh[j];
    float c_reg = 0.f;
    int len = lens[bt];
    __syncthreads();
    for (int t = 0; t < WE_; ++t) {
        float z = bjv;
        #pragma unroll
        for (int e = 0; e < EE; ++e) z += wih[e] * xs[t][e];
        const float4* h4 = (const float4*)hs;
        #pragma unroll
        for (int q = 0; q < HH / 4; ++q) {
            float4 hv = h4[q];
            z += whh[4*q+0] * hv.x + whh[4*q+1] * hv.y
               + whh[4*q+2] * hv.z + whh[4*q+3] * hv.w;
        }
        zs[j] = z;
        __syncthreads();
        if (j < HH) {
            float zi = zs[j], zf = zs[HH + j], zg = zs[2*HH + j], zo = zs[3*HH + j];
            float si = 1.f / (1.f + expf(-zi));
            float sf = 1.f / (1.f + expf(-zf));
            float so = 1.f / (1.f + expf(-zo));
            float tg = tanhf(zg);
            float c2 = sf * c_reg + si * tg;
            float h2 = so * tanhf(c2);
            bool valid = (t < len);
            float hn = valid ? h2 : hs[j];
            c_reg    = valid ? c2 : c_reg;
            hout[((size_t)bt * WE_ + t) * HH + j] = valid ? h2 : 0.f;
            hs[j] = hn;
        }
        __syncthreads();
    }
}

template<int CIN, int WIN, int COUT, int KDIM, int LOUT>
__global__ __launch_bounds__(256)
void conv_pool_simple(const float* __restrict__ x, const float* __restrict__ w,
                      const float* __restrict__ bias, float* __restrict__ pooled)
{
    constexpr int KW = KDIM / CIN;
    int bt = blockIdx.x;
    int co = blockIdx.y * 64 + (threadIdx.x & 63);
    int seg = threadIdx.x >> 6;
    __shared__ float part[4][64];
    float m = -INFINITY;
    for (int l = seg; l < LOUT; l += 4) {
        float acc = 0.f;
        for (int k = 0; k < KW; ++k) {
            const float* xr = x + ((size_t)bt * WIN + l + k) * CIN;
            const float* wr = w + ((size_t)co * CIN) * KW + k;
            for (int cc = 0; cc < CIN; ++cc) acc += xr[cc] * wr[(size_t)cc * KW];
        }
        m = fmaxf(m, acc);
    }
    part[seg][threadIdx.x & 63] = m;
    __syncthreads();
    if (threadIdx.x < 64) {
        float mm = fmaxf(fmaxf(part[0][threadIdx.x], part[1][threadIdx.x]),
                         fmaxf(part[2][threadIdx.x], part[3][threadIdx.x]));
        pooled[(size_t)bt * COUT + co] = mm + bias[co];
    }
}

// ---------------- launch ----------------
static inline int cdiv(int a, int b) { return (a + b - 1) / b; }

extern "C" void kernel_launch(void* const* d_in, const int* in_sizes, int n_in,
                              void* d_out, int out_size, void* d_ws, size_t ws_size,
                              hipStream_t stream) {
    const float* x_lin  = (const float*)d_in[0];
    const float* x_aco  = (const float*)d_in[1];
    const float* x_emo  = (const float*)d_in[2];
    const int*   wlen   = (const int*)  d_in[3];
    const float* convL_w = (const float*)d_in[5];
    const float* convL_b = (const float*)d_in[6];
    const float* convA_w = (const float*)d_in[7];
    const float* convA_b = (const float*)d_in[8];
    const float* convE_w = (const float*)d_in[9];
    const float* convE_b = (const float*)d_in[10];
    const float* hwL_Wp = (const float*)d_in[11];
    const float* hwL_bp = (const float*)d_in[12];
    const float* hwL_Wg = (const float*)d_in[13];
    const float* hwL_bg = (const float*)d_in[14];
    const float* hwA_Wp = (const float*)d_in[15];
    const float* hwA_bp = (const float*)d_in[16];
    const float* hwA_Wg = (const float*)d_in[17];
    const float* hwA_bg = (const float*)d_in[18];
    const float* hwE_Wp = (const float*)d_in[19];
    const float* hwE_bp = (const float*)d_in[20];
    const float* hwE_Wg = (const float*)d_in[21];
    const float* hwE_bg = (const float*)d_in[22];
    const float* lstm_Wih = (const float*)d_in[23];
    const float* lstm_Whh = (const float*)d_in[24];
    const float* lstm_bih = (const float*)d_in[25];
    const float* lstm_bhh = (const float*)d_in[26];
    float* out = (float*)d_out;

    // ---- workspace carve (256B aligned) ----
    char* p0 = (char*)d_ws;
    char* p = p0;
    auto alloc = [&](size_t bytes) { char* r = p; p += (bytes + 255) & ~(size_t)255; return r; };
    float* WpTL = (float*)alloc((size_t)CL * CL * 4);
    float* WgTL = (float*)alloc((size_t)CL * CL * 4);
    float* WpTA = (float*)alloc((size_t)CA * CA * 4);
    float* WgTA = (float*)alloc((size_t)CA * CA * 4);
    float* WpTE = (float*)alloc((size_t)CE * CE * 4);
    float* WgTE = (float*)alloc((size_t)CE * CE * 4);
    float* WihT = (float*)alloc((size_t)EE * 512 * 4);
    float* WhhT = (float*)alloc((size_t)HH * 512 * 4);
    unsigned short* whh_bf  = (unsigned short*)alloc((size_t)512 * 128 * 2);
    unsigned short* wihp_bf = (unsigned short*)alloc((size_t)512 * 32 * 2);
    void*  hbuf = (void*)alloc((size_t)BTOT * WE_ * HH * 4);
    float* pL   = (float*)alloc((size_t)BTOT * CL * 4);
    float* pA   = (float*)alloc((size_t)BTOT * CA * 4);
    float* pE   = (float*)alloc((size_t)BTOT * CE * 4);
    unsigned short* wtA = (unsigned short*)alloc((size_t)CA * KPA * 2);
    unsigned short* wtL = (unsigned short*)alloc((size_t)CL * KPL * 2);
    unsigned short* wtE = (unsigned short*)alloc((size_t)CE * KPE * 2);
    unsigned short* xlin_p = (unsigned short*)alloc((size_t)BTOT * WL_ * ELP * 2 + 64);
    unsigned short* xaco_p = (unsigned short*)alloc((size_t)BTOT * WA_ * EAP * 2 + 64);
    size_t need = (size_t)(p - p0);
    bool big = ws_size >= need;

    if (big) {
        prep_cvt<<<2048, 256, 0, stream>>>(hwL_Wp, WpTL, hwL_Wg, WgTL, hwA_Wp, WpTA, hwA_Wg, WgTA,
                                           hwE_Wp, WpTE, hwE_Wg, WgTE, lstm_Wih, lstm_Whh,
                                           convL_w, wtL, convE_w, wtE, convA_w, wtA,
                                           whh_bf, wihp_bf, x_aco, x_lin, xaco_p, xlin_p);
        lstm_only<<<LSTM_BLOCKS, 512, 0, stream>>>(
            x_emo, wihp_bf, whh_bf, lstm_bih, lstm_bhh, wlen, (unsigned short*)hbuf);
        conv_all<<<1536, 256, 0, stream>>>(xaco_p, wtA, convA_b, pA,
                                           xlin_p, wtL, convL_b, pL,
                                           (const unsigned short*)hbuf, wtE, convE_b, pE);
        highway_v2<<<HWA_BLOCKS + HWL_BLOCKS + HWE_BLOCKS, 256, 0, stream>>>(
            pL, pA, pE, WpTL, hwL_bp, WgTL, hwL_bg, WpTA, hwA_bp, WgTA, hwA_bg,
            WpTE, hwE_bp, WgTE, hwE_bg, out);
    } else {
        prep_fallback<<<512, 256, 0, stream>>>(hwL_Wp, WpTL, hwL_Wg, WgTL, hwA_Wp, WpTA, hwA_Wg, WgTA,
                                               hwE_Wp, WpTE, hwE_Wg, WgTE, lstm_Wih, WihT, lstm_Whh, WhhT);
        lstm_kernel_f32<<<BTOT, 512, 0, stream>>>(x_emo, wlen, WihT, WhhT, lstm_bih, lstm_bhh, (float*)hbuf);
        conv_pool_simple<EA, WA_, CA, KDIMA, LOUTA>
            <<<dim3(BTOT, CA / 64), 256, 0, stream>>>(x_aco, convA_w, convA_b, pA);
        conv_pool_simple<EL, WL_, CL, KDIML, LOUTL>
            <<<dim3(BTOT, CL / 64), 256, 0, stream>>>(x_lin, convL_w, convL_b, pL);
        conv_pool_simple<HH, WE_, CE, KDIME, LOUTE>
            <<<dim3(BTOT, CE / 64), 256, 0, stream>>>((const float*)hbuf, convE_w, convE_b, pE);
        highway_v2<<<HWA_BLOCKS + HWL_BLOCKS + HWE_BLOCKS, 256, 0, stream>>>(
            pL, pA, pE, WpTL, hwL_bp, WgTL, hwL_bg, WpTA, hwA_bp, WgTA, hwA_bg,
            WpTE, hwE_bp, WgTE, hwE_bg, out);
    }
}